// Round 1
// baseline (453.353 us; speedup 1.0000x reference)
//
#include <hip/hip_runtime.h>
#include <math.h>

// Problem constants
constexpr int Bsz = 4, T = 2048, Dm = 512, Hh = 8, Pp = 16, DHd = 64, Cc = 512;
constexpr int HFi = 64, WFi = 64;
constexpr float RADIUS = 0.08f;

// ---------------------------------------------------------------------------
// GEMM 1: v-projection. vflat[((b*8+head)*4096 + s)*64 + dh] =
//   sum_c fmap[(b*512+c)*4096 + s] * Wv[c*512 + head*64 + dh]
// A is (K x M) layout per batch (spatial index contiguous).
// grid = (4096/64, 8 heads, B), block = 256.
// ---------------------------------------------------------------------------
__global__ __launch_bounds__(256) void vproj_kernel(
    const float* __restrict__ fmap, const float* __restrict__ Wv,
    float* __restrict__ vflat) {
  __shared__ float As[16][64];
  __shared__ float Bs[16][64];
  const int b = blockIdx.z;
  const int s0 = blockIdx.x * 64;
  const int head = blockIdx.y;
  const int t = threadIdx.x;
  const int tm = t & 15, tn = t >> 4;

  float acc[4][4] = {};
  const float* Abase = fmap + (size_t)b * Cc * 4096 + s0;  // A[k][m] = Abase[k*4096+m]
  const float* Bbase = Wv + head * 64;                      // B[k][n] = Bbase[k*512+n]

  const int lrow = t >> 4;          // 0..15
  const int lcol = (t & 15) * 4;    // 0..60

  for (int k0 = 0; k0 < Cc; k0 += 16) {
    *(float4*)&As[lrow][lcol] = *(const float4*)&Abase[(size_t)(k0 + lrow) * 4096 + lcol];
    *(float4*)&Bs[lrow][lcol] = *(const float4*)&Bbase[(size_t)(k0 + lrow) * 512 + lcol];
    __syncthreads();
#pragma unroll
    for (int kk = 0; kk < 16; ++kk) {
      float4 a4 = *(float4*)&As[kk][tm * 4];
      float4 b4 = *(float4*)&Bs[kk][tn * 4];
      float ar[4] = {a4.x, a4.y, a4.z, a4.w};
      float br[4] = {b4.x, b4.y, b4.z, b4.w};
#pragma unroll
      for (int i = 0; i < 4; ++i)
#pragma unroll
        for (int j = 0; j < 4; ++j) acc[i][j] = fmaf(ar[i], br[j], acc[i][j]);
    }
    __syncthreads();
  }

  float* out = vflat + ((size_t)(b * 8 + head) * 4096 + s0) * 64;
#pragma unroll
  for (int i = 0; i < 4; ++i) {
    int m = tm * 4 + i;
    float4 w = make_float4(acc[i][0], acc[i][1], acc[i][2], acc[i][3]);
    *(float4*)&out[(size_t)m * 64 + tn * 4] = w;
  }
}

// ---------------------------------------------------------------------------
// Generic row-major-A GEMM: C[m][n] = sum_k A[m*lda+k]*Bm[k*ldb+n] + bias[n]
// grid = (M/64, N/64), block = 256. K multiple of 16, M/N multiples of 64.
// ---------------------------------------------------------------------------
__global__ __launch_bounds__(256) void gemm_rm_kernel(
    const float* __restrict__ A, int lda, const float* __restrict__ Bm, int ldb,
    const float* __restrict__ bias, float* __restrict__ C, int ldc, int K) {
  __shared__ float As[16][64];
  __shared__ float Bs[16][64];
  const int m0 = blockIdx.x * 64;
  const int n0 = blockIdx.y * 64;
  const int t = threadIdx.x;
  const int tm = t & 15, tn = t >> 4;

  float acc[4][4] = {};

  const int amm = t >> 2;          // 0..63
  const int akk = (t & 3) * 4;     // 0..12
  const int brow = t >> 4;         // 0..15
  const int bcol = (t & 15) * 4;   // 0..60

  for (int k0 = 0; k0 < K; k0 += 16) {
    float4 av = *(const float4*)&A[(size_t)(m0 + amm) * lda + k0 + akk];
    As[akk + 0][amm] = av.x;
    As[akk + 1][amm] = av.y;
    As[akk + 2][amm] = av.z;
    As[akk + 3][amm] = av.w;
    *(float4*)&Bs[brow][bcol] = *(const float4*)&Bm[(size_t)(k0 + brow) * ldb + n0 + bcol];
    __syncthreads();
#pragma unroll
    for (int kk = 0; kk < 16; ++kk) {
      float4 a4 = *(float4*)&As[kk][tm * 4];
      float4 b4 = *(float4*)&Bs[kk][tn * 4];
      float ar[4] = {a4.x, a4.y, a4.z, a4.w};
      float br[4] = {b4.x, b4.y, b4.z, b4.w};
#pragma unroll
      for (int i = 0; i < 4; ++i)
#pragma unroll
        for (int j = 0; j < 4; ++j) acc[i][j] = fmaf(ar[i], br[j], acc[i][j]);
    }
    __syncthreads();
  }

  float4 bv = *(const float4*)&bias[n0 + tn * 4];
  float br[4] = {bv.x, bv.y, bv.z, bv.w};
#pragma unroll
  for (int i = 0; i < 4; ++i) {
    int m = m0 + tm * 4 + i;
    float4 w = make_float4(acc[i][0] + br[0], acc[i][1] + br[1],
                           acc[i][2] + br[2], acc[i][3] + br[3]);
    *(float4*)&C[(size_t)m * ldc + n0 + tn * 4] = w;
  }
}

// ---------------------------------------------------------------------------
// Fused softmax + bilinear sampling.
// One block per (b,t): 4 waves, each wave handles heads {w, w+4}; lane = dh.
// ctx[(b*T+t)*512 + h*64 + dh] = sum_p attn[p] * bilinear(vflat[b,h], samp_p)[dh]
// ---------------------------------------------------------------------------
__global__ __launch_bounds__(256) void sample_kernel(
    const float* __restrict__ ref_xy, const float* __restrict__ offbuf,
    const float* __restrict__ logitbuf, const float* __restrict__ vflat,
    float* __restrict__ ctx) {
  const int bt = blockIdx.x;        // b*T + t
  const int b = bt >> 11;           // T = 2048
  const int wave = threadIdx.x >> 6;
  const int lane = threadIdx.x & 63;

  const float ref_x = ref_xy[bt * 2 + 0];
  const float ref_y = ref_xy[bt * 2 + 1];

  for (int h = wave; h < Hh; h += 4) {
    // softmax over P=16 logits (uniform across lanes; broadcast loads)
    const float* lg = logitbuf + (size_t)bt * 128 + h * 16;
    float lv[16];
    float mx = -1e30f;
#pragma unroll
    for (int p = 0; p < 16; ++p) {
      lv[p] = lg[p];
      mx = fmaxf(mx, lv[p]);
    }
    float sum = 0.f;
#pragma unroll
    for (int p = 0; p < 16; ++p) {
      lv[p] = __expf(lv[p] - mx);
      sum += lv[p];
    }
    const float inv = 1.0f / sum;

    const float* of = offbuf + (size_t)bt * 256 + h * 32;
    const float* vb = vflat + (size_t)(b * 8 + h) * 4096 * 64 + lane;

    float acc = 0.f;
#pragma unroll 4
    for (int p = 0; p < 16; ++p) {
      const float aw = lv[p] * inv;
      const float ix = (ref_x + RADIUS * of[p * 2 + 0]) * (float)(WFi - 1);
      const float iy = (ref_y + RADIUS * of[p * 2 + 1]) * (float)(HFi - 1);
      const float ix0f = floorf(ix), iy0f = floorf(iy);
      const float fx = ix - ix0f, fy = iy - iy0f;
      const int ix0 = (int)ix0f, iy0 = (int)iy0f;

      const float w00 = (1.f - fx) * (1.f - fy) * aw;
      const float w10 = fx * (1.f - fy) * aw;
      const float w01 = (1.f - fx) * fy * aw;
      const float w11 = fx * fy * aw;

#pragma unroll
      for (int c = 0; c < 4; ++c) {
        const int xi = ix0 + (c & 1);
        const int yi = iy0 + (c >> 1);
        const float w = (c == 0) ? w00 : (c == 1) ? w10 : (c == 2) ? w01 : w11;
        const bool valid = (xi >= 0) & (xi < WFi) & (yi >= 0) & (yi < HFi);
        const int xc = min(max(xi, 0), WFi - 1);
        const int yc = min(max(yi, 0), HFi - 1);
        const float val = vb[(size_t)(yc * WFi + xc) * 64];
        acc = fmaf(valid ? w : 0.f, val, acc);
      }
    }
    ctx[(size_t)bt * 512 + h * 64 + lane] = acc;
  }
}

// ---------------------------------------------------------------------------
extern "C" void kernel_launch(void* const* d_in, const int* in_sizes, int n_in,
                              void* d_out, int out_size, void* d_ws, size_t ws_size,
                              hipStream_t stream) {
  const float* q      = (const float*)d_in[0];
  const float* fmap   = (const float*)d_in[1];
  const float* ref_xy = (const float*)d_in[2];
  const float* Wv     = (const float*)d_in[3];
  const float* W_off  = (const float*)d_in[4];
  const float* b_off  = (const float*)d_in[5];
  const float* W_w    = (const float*)d_in[6];
  const float* b_w    = (const float*)d_in[7];
  const float* W_out  = (const float*)d_in[8];
  const float* b_out  = (const float*)d_in[9];
  float* out = (float*)d_out;

  float* ws = (float*)d_ws;
  float* vflat    = ws;                      // B*H*4096*64      = 8,388,608 floats
  float* offbuf   = vflat + 8388608;         // B*T*256          = 2,097,152
  float* logitbuf = offbuf + 2097152;        // B*T*128          = 1,048,576
  float* ctx      = logitbuf + 1048576;      // B*T*512          = 4,194,304

  // 1) value projection into gather-friendly layout
  vproj_kernel<<<dim3(4096 / 64, Hh, Bsz), 256, 0, stream>>>(fmap, Wv, vflat);

  // 2) offset + attention-logit projections (M = B*T = 8192)
  gemm_rm_kernel<<<dim3(8192 / 64, 256 / 64), 256, 0, stream>>>(
      q, 512, W_off, 256, b_off, offbuf, 256, 512);
  gemm_rm_kernel<<<dim3(8192 / 64, 128 / 64), 256, 0, stream>>>(
      q, 512, W_w, 128, b_w, logitbuf, 128, 512);

  // 3) fused softmax + bilinear gather -> ctx (B,T,D)
  sample_kernel<<<dim3(Bsz * T), 256, 0, stream>>>(ref_xy, offbuf, logitbuf, vflat, ctx);

  // 4) output projection
  gemm_rm_kernel<<<dim3(8192 / 64, 512 / 64), 256, 0, stream>>>(
      ctx, 512, W_out, 512, b_out, out, 512, 512);
}

// Round 2
// 376.084 us; speedup vs baseline: 1.2055x; 1.2055x over previous
//
#include <hip/hip_runtime.h>
#include <hip/hip_bf16.h>
#include <math.h>

// Problem constants
constexpr int Bsz = 4, T = 2048, Hh = 8;
constexpr int HFi = 64, WFi = 64;
constexpr float RADIUS = 0.08f;

typedef __bf16 bf16x8 __attribute__((ext_vector_type(8)));
typedef float f32x4 __attribute__((ext_vector_type(4)));

// ---------------------------------------------------------------------------
// Tiled transpose + fp32->bf16 convert: in (R x C row-major) -> out (C x R).
// grid = (C/32, R/32, batches), block = 256 (32x8).
// ---------------------------------------------------------------------------
__global__ __launch_bounds__(256) void transpose_to_bf16(
    const float* __restrict__ in, __hip_bfloat16* __restrict__ out,
    int R, int C) {
  __shared__ float tile[32][33];
  const size_t bo = (size_t)blockIdx.z * R * C;
  const int c0 = blockIdx.x * 32, r0 = blockIdx.y * 32;
  const int tx = threadIdx.x & 31, ty = threadIdx.x >> 5;
#pragma unroll
  for (int i = ty; i < 32; i += 8)
    tile[i][tx] = in[bo + (size_t)(r0 + i) * C + c0 + tx];
  __syncthreads();
#pragma unroll
  for (int i = ty; i < 32; i += 8)
    out[bo + (size_t)(c0 + i) * R + r0 + tx] = __float2bfloat16(tile[tx][i]);
}

// ---------------------------------------------------------------------------
// bf16 MFMA GEMM, B^T layout: C[m][n] = sum_k A[m*K+k] * Bm[n*K+k] (+bias)
// 128x128 block tile, BK=64, 4 waves (2x2), each wave 64x64 via 4x4 MFMA tiles.
// MODE 0: C fp32 row-major ldc=512, +bias.  (out-projection)
// MODE 1: C bf16 scattered to vflat[((b*8+head)*4096+s)*64+dh], n=(head,dh).
// grid = (M/128, N/128, batches)
// ---------------------------------------------------------------------------
template <int MODE>
__global__ __launch_bounds__(256) void mfma_gemm_bt(
    const __hip_bfloat16* __restrict__ A, const __hip_bfloat16* __restrict__ Bm,
    const float* __restrict__ bias, void* __restrict__ Cout, int M, int K) {
  __shared__ unsigned short As[128][72];  // padded: 72*2=144B row stride
  __shared__ unsigned short Bs[128][72];
  const int tid = threadIdx.x;
  const int lane = tid & 63;
  const int wave = tid >> 6;
  const int wm = (wave & 1) * 64, wn = (wave >> 1) * 64;
  const int l15 = lane & 15, quad = lane >> 4;
  const int m0 = blockIdx.x * 128, n0 = blockIdx.y * 128;
  const int b = blockIdx.z;
  const __hip_bfloat16* Ab = A + (size_t)b * M * K;

  f32x4 acc[4][4] = {};

  const int arow = tid >> 3;       // 0..31 (+i*32)
  const int acol = (tid & 7) * 8;  // bf16 col offset 0..56

  for (int k0 = 0; k0 < K; k0 += 64) {
#pragma unroll
    for (int i = 0; i < 4; ++i) {
      const int r = arow + i * 32;
      *(float4*)&As[r][acol] = *(const float4*)(Ab + (size_t)(m0 + r) * K + k0 + acol);
      *(float4*)&Bs[r][acol] = *(const float4*)(Bm + (size_t)(n0 + r) * K + k0 + acol);
    }
    __syncthreads();
#pragma unroll
    for (int ks = 0; ks < 2; ++ks) {
      bf16x8 af[4], bfr[4];
#pragma unroll
      for (int i = 0; i < 4; ++i)
        af[i] = *(const bf16x8*)&As[wm + i * 16 + l15][ks * 32 + quad * 8];
#pragma unroll
      for (int j = 0; j < 4; ++j)
        bfr[j] = *(const bf16x8*)&Bs[wn + j * 16 + l15][ks * 32 + quad * 8];
#pragma unroll
      for (int i = 0; i < 4; ++i)
#pragma unroll
        for (int j = 0; j < 4; ++j)
          acc[i][j] = __builtin_amdgcn_mfma_f32_16x16x32_bf16(af[i], bfr[j], acc[i][j], 0, 0, 0);
    }
    __syncthreads();
  }

  if (MODE == 0) {
    float* C = (float*)Cout;
#pragma unroll
    for (int i = 0; i < 4; ++i) {
      const int mbase = m0 + wm + i * 16 + quad * 4;
#pragma unroll
      for (int j = 0; j < 4; ++j) {
        const int n = n0 + wn + j * 16 + l15;
        const float bb = bias[n];
#pragma unroll
        for (int r = 0; r < 4; ++r)
          C[(size_t)(mbase + r) * 512 + n] = acc[i][j][r] + bb;
      }
    }
  } else {
    __hip_bfloat16* C = (__hip_bfloat16*)Cout + (size_t)b * 8 * 4096 * 64;
#pragma unroll
    for (int i = 0; i < 4; ++i) {
      const int mbase = m0 + wm + i * 16 + quad * 4;  // spatial index s
#pragma unroll
      for (int j = 0; j < 4; ++j) {
        const int ng = n0 + wn + j * 16 + l15;
        const int head = ng >> 6, dh = ng & 63;
#pragma unroll
        for (int r = 0; r < 4; ++r)
          C[(size_t)head * (4096 * 64) + (size_t)(mbase + r) * 64 + dh] =
              __float2bfloat16(acc[i][j][r]);
      }
    }
  }
}

// ---------------------------------------------------------------------------
// fp32 GEMM for position-sensitive projections (offsets, logits).
// C[m][n] = sum_k A[m*lda+k]*Bm[k*ldb+n] + bias[n]
// ---------------------------------------------------------------------------
__global__ __launch_bounds__(256) void gemm_rm_kernel(
    const float* __restrict__ A, int lda, const float* __restrict__ Bm, int ldb,
    const float* __restrict__ bias, float* __restrict__ C, int ldc, int K) {
  __shared__ float As[16][64];
  __shared__ float Bs[16][64];
  const int m0 = blockIdx.x * 64;
  const int n0 = blockIdx.y * 64;
  const int t = threadIdx.x;
  const int tm = t & 15, tn = t >> 4;

  float acc[4][4] = {};

  const int amm = t >> 2;
  const int akk = (t & 3) * 4;
  const int brow = t >> 4;
  const int bcol = (t & 15) * 4;

  for (int k0 = 0; k0 < K; k0 += 16) {
    float4 av = *(const float4*)&A[(size_t)(m0 + amm) * lda + k0 + akk];
    As[akk + 0][amm] = av.x;
    As[akk + 1][amm] = av.y;
    As[akk + 2][amm] = av.z;
    As[akk + 3][amm] = av.w;
    *(float4*)&Bs[brow][bcol] = *(const float4*)&Bm[(size_t)(k0 + brow) * ldb + n0 + bcol];
    __syncthreads();
#pragma unroll
    for (int kk = 0; kk < 16; ++kk) {
      float4 a4 = *(float4*)&As[kk][tm * 4];
      float4 b4 = *(float4*)&Bs[kk][tn * 4];
      float ar[4] = {a4.x, a4.y, a4.z, a4.w};
      float br[4] = {b4.x, b4.y, b4.z, b4.w};
#pragma unroll
      for (int i = 0; i < 4; ++i)
#pragma unroll
        for (int j = 0; j < 4; ++j) acc[i][j] = fmaf(ar[i], br[j], acc[i][j]);
    }
    __syncthreads();
  }

  float4 bv = *(const float4*)&bias[n0 + tn * 4];
  float br[4] = {bv.x, bv.y, bv.z, bv.w};
#pragma unroll
  for (int i = 0; i < 4; ++i) {
    int m = m0 + tm * 4 + i;
    float4 w = make_float4(acc[i][0] + br[0], acc[i][1] + br[1],
                           acc[i][2] + br[2], acc[i][3] + br[3]);
    *(float4*)&C[(size_t)m * ldc + n0 + tn * 4] = w;
  }
}

// ---------------------------------------------------------------------------
// Fused softmax + bilinear sampling. vflat is bf16; ctx written as bf16.
// One block per (b,t): 4 waves, each wave heads {w, w+4}; lane = dh.
// ---------------------------------------------------------------------------
__global__ __launch_bounds__(256) void sample_kernel(
    const float* __restrict__ ref_xy, const float* __restrict__ offbuf,
    const float* __restrict__ logitbuf, const __hip_bfloat16* __restrict__ vflat,
    __hip_bfloat16* __restrict__ ctx) {
  const int bt = blockIdx.x;
  const int b = bt >> 11;  // T = 2048
  const int wave = threadIdx.x >> 6;
  const int lane = threadIdx.x & 63;

  const float ref_x = ref_xy[bt * 2 + 0];
  const float ref_y = ref_xy[bt * 2 + 1];

  for (int h = wave; h < Hh; h += 4) {
    const float* lg = logitbuf + (size_t)bt * 128 + h * 16;
    float lv[16];
    float mx = -1e30f;
#pragma unroll
    for (int p = 0; p < 16; ++p) {
      lv[p] = lg[p];
      mx = fmaxf(mx, lv[p]);
    }
    float sum = 0.f;
#pragma unroll
    for (int p = 0; p < 16; ++p) {
      lv[p] = __expf(lv[p] - mx);
      sum += lv[p];
    }
    const float inv = 1.0f / sum;

    const float* of = offbuf + (size_t)bt * 256 + h * 32;
    const __hip_bfloat16* vb = vflat + (size_t)(b * 8 + h) * 4096 * 64 + lane;

    float acc = 0.f;
#pragma unroll 4
    for (int p = 0; p < 16; ++p) {
      const float aw = lv[p] * inv;
      const float ix = (ref_x + RADIUS * of[p * 2 + 0]) * (float)(WFi - 1);
      const float iy = (ref_y + RADIUS * of[p * 2 + 1]) * (float)(HFi - 1);
      const float ix0f = floorf(ix), iy0f = floorf(iy);
      const float fx = ix - ix0f, fy = iy - iy0f;
      const int ix0 = (int)ix0f, iy0 = (int)iy0f;

      const float w00 = (1.f - fx) * (1.f - fy) * aw;
      const float w10 = fx * (1.f - fy) * aw;
      const float w01 = (1.f - fx) * fy * aw;
      const float w11 = fx * fy * aw;

#pragma unroll
      for (int c = 0; c < 4; ++c) {
        const int xi = ix0 + (c & 1);
        const int yi = iy0 + (c >> 1);
        const float w = (c == 0) ? w00 : (c == 1) ? w10 : (c == 2) ? w01 : w11;
        const bool valid = (xi >= 0) & (xi < WFi) & (yi >= 0) & (yi < HFi);
        const int xc = min(max(xi, 0), WFi - 1);
        const int yc = min(max(yi, 0), HFi - 1);
        const float val = __bfloat162float(vb[(size_t)(yc * WFi + xc) * 64]);
        acc = fmaf(valid ? w : 0.f, val, acc);
      }
    }
    ctx[(size_t)bt * 512 + h * 64 + lane] = __float2bfloat16(acc);
  }
}

// ---------------------------------------------------------------------------
extern "C" void kernel_launch(void* const* d_in, const int* in_sizes, int n_in,
                              void* d_out, int out_size, void* d_ws, size_t ws_size,
                              hipStream_t stream) {
  const float* q      = (const float*)d_in[0];
  const float* fmap   = (const float*)d_in[1];
  const float* ref_xy = (const float*)d_in[2];
  const float* Wv     = (const float*)d_in[3];
  const float* W_off  = (const float*)d_in[4];
  const float* b_off  = (const float*)d_in[5];
  const float* W_w    = (const float*)d_in[6];
  const float* b_w    = (const float*)d_in[7];
  const float* W_out  = (const float*)d_in[8];
  const float* b_out  = (const float*)d_in[9];
  float* out = (float*)d_out;

  // workspace layout (bytes)
  char* ws = (char*)d_ws;
  float* offbuf   = (float*)ws;                       ws += 2097152 * 4;  // B*T*256
  float* logitbuf = (float*)ws;                       ws += 1048576 * 4;  // B*T*128
  __hip_bfloat16* fmapT  = (__hip_bfloat16*)ws;       ws += 8388608 * 2;  // B*4096*512
  __hip_bfloat16* WvT    = (__hip_bfloat16*)ws;       ws += 262144 * 2;   // 512*512
  __hip_bfloat16* WoutT  = (__hip_bfloat16*)ws;       ws += 262144 * 2;   // 512*512
  __hip_bfloat16* vflat  = (__hip_bfloat16*)ws;       ws += 8388608 * 2;  // B*8*4096*64
  __hip_bfloat16* ctxb   = (__hip_bfloat16*)ws;       ws += 4194304 * 2;  // B*T*512

  // 0) converts/transposes to bf16 (B^T layouts for MFMA)
  transpose_to_bf16<<<dim3(4096 / 32, 512 / 32, Bsz), 256, 0, stream>>>(fmap, fmapT, 512, 4096);
  transpose_to_bf16<<<dim3(512 / 32, 512 / 32, 1), 256, 0, stream>>>(Wv, WvT, 512, 512);
  transpose_to_bf16<<<dim3(512 / 32, 512 / 32, 1), 256, 0, stream>>>(W_out, WoutT, 512, 512);

  // 1) offset + logit projections in fp32 (position-sensitive)
  gemm_rm_kernel<<<dim3(8192 / 64, 256 / 64), 256, 0, stream>>>(
      q, 512, W_off, 256, b_off, offbuf, 256, 512);
  gemm_rm_kernel<<<dim3(8192 / 64, 128 / 64), 256, 0, stream>>>(
      q, 512, W_w, 128, b_w, logitbuf, 128, 512);

  // 2) value projection: bf16 MFMA, scatter into vflat (b,h,s,dh) bf16
  mfma_gemm_bt<1><<<dim3(4096 / 128, 512 / 128, Bsz), 256, 0, stream>>>(
      fmapT, WvT, nullptr, vflat, 4096, 512);

  // 3) fused softmax + bilinear gather -> ctx bf16
  sample_kernel<<<dim3(Bsz * T), 256, 0, stream>>>(ref_xy, offbuf, logitbuf, vflat, ctxb);

  // 4) output projection: bf16 MFMA + bias -> fp32 out
  mfma_gemm_bt<0><<<dim3(8192 / 128, 512 / 128, 1), 256, 0, stream>>>(
      ctxb, WoutT, b_out, out, 8192, 512);
}

// Round 3
// 250.047 us; speedup vs baseline: 1.8131x; 1.5041x over previous
//
#include <hip/hip_runtime.h>
#include <hip/hip_bf16.h>
#include <math.h>

// Problem constants
constexpr int Bsz = 4, T = 2048, Hh = 8;
constexpr int HFi = 64, WFi = 64;
constexpr float RADIUS = 0.08f;

typedef __bf16 bf16x8 __attribute__((ext_vector_type(8)));
typedef float f32x4 __attribute__((ext_vector_type(4)));

// ---------------------------------------------------------------------------
// Tiled transpose + fp32->bf16 convert: in (R x C row-major) -> out (C x R).
// ---------------------------------------------------------------------------
__global__ __launch_bounds__(256) void transpose_to_bf16(
    const float* __restrict__ in, __hip_bfloat16* __restrict__ out,
    int R, int C) {
  __shared__ float tile[32][33];
  const size_t bo = (size_t)blockIdx.z * R * C;
  const int c0 = blockIdx.x * 32, r0 = blockIdx.y * 32;
  const int tx = threadIdx.x & 31, ty = threadIdx.x >> 5;
#pragma unroll
  for (int i = ty; i < 32; i += 8)
    tile[i][tx] = in[bo + (size_t)(r0 + i) * C + c0 + tx];
  __syncthreads();
#pragma unroll
  for (int i = ty; i < 32; i += 8)
    out[bo + (size_t)(c0 + i) * R + r0 + tx] = __float2bfloat16(tile[tx][i]);
}

// ---------------------------------------------------------------------------
// q split into hi/lo bf16: qsplit[m][0:512]=hi, [512:1024]=lo.
// one thread per 4 consecutive k. grid = 8192*128/256.
// ---------------------------------------------------------------------------
__global__ __launch_bounds__(256) void split_q_kernel(
    const float* __restrict__ q, __hip_bfloat16* __restrict__ qsplit) {
  const int idx = blockIdx.x * 256 + threadIdx.x;  // 8192*128
  const int m = idx >> 7, kq = (idx & 127) * 4;
  float4 v = *(const float4*)&q[(size_t)m * 512 + kq];
  union { __hip_bfloat16 b[4]; ushort4 u; } hi, lo;
  float f[4] = {v.x, v.y, v.z, v.w};
#pragma unroll
  for (int i = 0; i < 4; ++i) {
    hi.b[i] = __float2bfloat16(f[i]);
    lo.b[i] = __float2bfloat16(f[i] - __bfloat162float(hi.b[i]));
  }
  *(ushort4*)&qsplit[(size_t)m * 1024 + kq] = hi.u;
  *(ushort4*)&qsplit[(size_t)m * 1024 + 512 + kq] = lo.u;
}

// ---------------------------------------------------------------------------
// Build Wcat[n][k'] (384 x 1536, B^T layout) = [W_hi | W_hi | W_lo] stacking
// for split-bf16 GEMM, where W[k][n] = n<256 ? W_off[k][n] : W_w[k][n-256].
// Also bias_cat[384] = [b_off | b_w].
// ---------------------------------------------------------------------------
__global__ __launch_bounds__(256) void prep_w_kernel(
    const float* __restrict__ W_off, const float* __restrict__ W_w,
    const float* __restrict__ b_off, const float* __restrict__ b_w,
    __hip_bfloat16* __restrict__ Wcat, float* __restrict__ bias_cat) {
  const int idx = blockIdx.x * 256 + threadIdx.x;  // 384*1536
  if (idx >= 384 * 1536) return;
  const int n = idx / 1536, kp = idx % 1536;
  const int k = kp & 511;
  const float w = (n < 256) ? W_off[(size_t)k * 256 + n] : W_w[(size_t)k * 128 + (n - 256)];
  const __hip_bfloat16 h = __float2bfloat16(w);
  const __hip_bfloat16 o =
      (kp < 1024) ? h : __float2bfloat16(w - __bfloat162float(h));
  Wcat[(size_t)n * 1536 + kp] = o;
  if (idx < 384) bias_cat[idx] = (idx < 256) ? b_off[idx] : b_w[idx - 256];
}

// ---------------------------------------------------------------------------
// bf16 MFMA GEMM, B^T layout: C[m][n] = sum_k A[m*lda+k] * Bm[n*ldb+k] (+bias)
// 128x128 tile, BK=64, 4 waves (2x2), each wave 64x64 via 4x4 16x16x32 MFMAs.
// MODE 0: C fp32 row-major ldc, +bias.
// MODE 1: C bf16 scattered to vflat[((b*8+head)*4096+s)*64+dh].
// AWRAP: for split-K GEMM, A k-index k0>=1024 reads A at k0-1024 (hi block).
// ---------------------------------------------------------------------------
template <int MODE, bool AWRAP>
__global__ __launch_bounds__(256) void mfma_gemm_bt(
    const __hip_bfloat16* __restrict__ A, int lda,
    const __hip_bfloat16* __restrict__ Bm, int ldb,
    const float* __restrict__ bias, void* __restrict__ Cout,
    int M, int Kt, int ldc) {
  __shared__ unsigned short As[128][72];
  __shared__ unsigned short Bs[128][72];
  const int tid = threadIdx.x;
  const int lane = tid & 63;
  const int wave = tid >> 6;
  const int wm = (wave & 1) * 64, wn = (wave >> 1) * 64;
  const int l15 = lane & 15, quad = lane >> 4;
  const int m0 = blockIdx.x * 128, n0 = blockIdx.y * 128;
  const int b = blockIdx.z;
  const __hip_bfloat16* Ab = A + (size_t)b * M * lda;

  f32x4 acc[4][4] = {};

  const int arow = tid >> 3;
  const int acol = (tid & 7) * 8;

  for (int k0 = 0; k0 < Kt; k0 += 64) {
    const int ka = AWRAP ? (k0 >= 1024 ? k0 - 1024 : k0) : k0;
#pragma unroll
    for (int i = 0; i < 4; ++i) {
      const int r = arow + i * 32;
      *(float4*)&As[r][acol] = *(const float4*)(Ab + (size_t)(m0 + r) * lda + ka + acol);
      *(float4*)&Bs[r][acol] = *(const float4*)(Bm + (size_t)(n0 + r) * ldb + k0 + acol);
    }
    __syncthreads();
#pragma unroll
    for (int ks = 0; ks < 2; ++ks) {
      bf16x8 af[4], bfr[4];
#pragma unroll
      for (int i = 0; i < 4; ++i)
        af[i] = *(const bf16x8*)&As[wm + i * 16 + l15][ks * 32 + quad * 8];
#pragma unroll
      for (int j = 0; j < 4; ++j)
        bfr[j] = *(const bf16x8*)&Bs[wn + j * 16 + l15][ks * 32 + quad * 8];
#pragma unroll
      for (int i = 0; i < 4; ++i)
#pragma unroll
        for (int j = 0; j < 4; ++j)
          acc[i][j] = __builtin_amdgcn_mfma_f32_16x16x32_bf16(af[i], bfr[j], acc[i][j], 0, 0, 0);
    }
    __syncthreads();
  }

  if (MODE == 0) {
    float* C = (float*)Cout;
#pragma unroll
    for (int i = 0; i < 4; ++i) {
      const int mbase = m0 + wm + i * 16 + quad * 4;
#pragma unroll
      for (int j = 0; j < 4; ++j) {
        const int n = n0 + wn + j * 16 + l15;
        const float bb = bias[n];
#pragma unroll
        for (int r = 0; r < 4; ++r)
          C[(size_t)(mbase + r) * ldc + n] = acc[i][j][r] + bb;
      }
    }
  } else {
    __hip_bfloat16* C = (__hip_bfloat16*)Cout + (size_t)b * 8 * 4096 * 64;
#pragma unroll
    for (int i = 0; i < 4; ++i) {
      const int mbase = m0 + wm + i * 16 + quad * 4;  // spatial index s
#pragma unroll
      for (int j = 0; j < 4; ++j) {
        const int ng = n0 + wn + j * 16 + l15;
        const int head = ng >> 6, dh = ng & 63;
#pragma unroll
        for (int r = 0; r < 4; ++r)
          C[(size_t)head * (4096 * 64) + (size_t)(mbase + r) * 64 + dh] =
              __float2bfloat16(acc[i][j][r]);
      }
    }
  }
}

// ---------------------------------------------------------------------------
// Fused softmax + bilinear sampling, dh-pair packed.
// Block = (b,t), 4 waves; wave handles heads {w, w+4}.
// Lanes 0..31: points 0..7, lanes 32..63: points 8..15; lane k covers dh pair
// (2k, 2k+1) via uint loads of bf16 vflat. Halves combined with shfl_xor(32).
// Corner addressing: clamped base xA=clamp(ix0,0,62) etc., per-axis weight
// remap gives exact zeros-padding semantics; corners are base, +128B, +8KB.
// ---------------------------------------------------------------------------
__global__ __launch_bounds__(256) void sample_kernel(
    const float* __restrict__ ref_xy, const float* __restrict__ projbuf,
    const unsigned int* __restrict__ vflat2, unsigned int* __restrict__ ctx2) {
  const int bt = blockIdx.x;
  const int b = bt >> 11;  // T = 2048
  const int wave = threadIdx.x >> 6;
  const int lane = threadIdx.x & 63;
  const int l31 = lane & 31;
  const bool hiHalf = lane >= 32;

  const float ref_x = ref_xy[bt * 2 + 0];
  const float ref_y = ref_xy[bt * 2 + 1];
  const float* prow = projbuf + (size_t)bt * 384;

  for (int h = wave; h < Hh; h += 4) {
    // softmax over P=16 logits (wave-uniform broadcast loads)
    const float* lg = prow + 256 + h * 16;
    float lv[16];
    float mx = -1e30f;
#pragma unroll
    for (int p = 0; p < 16; ++p) {
      lv[p] = lg[p];
      mx = fmaxf(mx, lv[p]);
    }
    float sum = 0.f;
#pragma unroll
    for (int p = 0; p < 16; ++p) {
      lv[p] = __expf(lv[p] - mx);
      sum += lv[p];
    }
    const float inv = 1.0f / sum;

    const float* of = prow + h * 32 + (hiHalf ? 16 : 0);
    const unsigned int* vb = vflat2 + (size_t)(b * 8 + h) * (4096 * 32) + l31;

    float acc0 = 0.f, acc1 = 0.f;
#pragma unroll
    for (int pp = 0; pp < 8; ++pp) {
      const float aw = inv * (hiHalf ? lv[pp + 8] : lv[pp]);
      const float2 o2 = *(const float2*)&of[pp * 2];
      const float ix = (ref_x + RADIUS * o2.x) * (float)(WFi - 1);
      const float iy = (ref_y + RADIUS * o2.y) * (float)(HFi - 1);
      const float ix0f = floorf(ix), iy0f = floorf(iy);
      const float fx = ix - ix0f, fy = iy - iy0f;
      const int ix0 = (int)ix0f, iy0 = (int)iy0f;

      float wx0 = 1.f - fx, wx1 = fx;
      float wy0 = 1.f - fy, wy1 = fy;
      if (ix0 == -1) { wx0 = fx; wx1 = 0.f; }
      if (ix0 == 63) { wx0 = 0.f; wx1 = 1.f - fx; }
      if (ix0 < -1 || ix0 > 63) { wx0 = 0.f; wx1 = 0.f; }
      if (iy0 == -1) { wy0 = fy; wy1 = 0.f; }
      if (iy0 == 63) { wy0 = 0.f; wy1 = 1.f - fy; }
      if (iy0 < -1 || iy0 > 63) { wy0 = 0.f; wy1 = 0.f; }
      const int xA = min(max(ix0, 0), WFi - 2);
      const int yA = min(max(iy0, 0), HFi - 2);

      wy0 *= aw;
      wy1 *= aw;
      const float w00 = wx0 * wy0, w10 = wx1 * wy0;
      const float w01 = wx0 * wy1, w11 = wx1 * wy1;

      const unsigned int* r0 = vb + (size_t)(yA * WFi + xA) * 32;
      const unsigned int* r1 = r0 + WFi * 32;
      const unsigned int v00 = r0[0], v10 = r0[32];
      const unsigned int v01 = r1[0], v11 = r1[32];

      const float e00 = __uint_as_float(v00 << 16), o00 = __uint_as_float(v00 & 0xffff0000u);
      const float e10 = __uint_as_float(v10 << 16), o10 = __uint_as_float(v10 & 0xffff0000u);
      const float e01 = __uint_as_float(v01 << 16), o01 = __uint_as_float(v01 & 0xffff0000u);
      const float e11 = __uint_as_float(v11 << 16), o11 = __uint_as_float(v11 & 0xffff0000u);

      acc0 = fmaf(w00, e00, acc0);
      acc1 = fmaf(w00, o00, acc1);
      acc0 = fmaf(w10, e10, acc0);
      acc1 = fmaf(w10, o10, acc1);
      acc0 = fmaf(w01, e01, acc0);
      acc1 = fmaf(w01, o01, acc1);
      acc0 = fmaf(w11, e11, acc0);
      acc1 = fmaf(w11, o11, acc1);
    }

    acc0 += __shfl_xor(acc0, 32, 64);
    acc1 += __shfl_xor(acc1, 32, 64);
    if (!hiHalf) {
      union { __hip_bfloat16 b; unsigned short u; } c0, c1;
      c0.b = __float2bfloat16(acc0);
      c1.b = __float2bfloat16(acc1);
      ctx2[(size_t)bt * 256 + h * 32 + l31] = ((unsigned int)c1.u << 16) | c0.u;
    }
  }
}

// ---------------------------------------------------------------------------
extern "C" void kernel_launch(void* const* d_in, const int* in_sizes, int n_in,
                              void* d_out, int out_size, void* d_ws, size_t ws_size,
                              hipStream_t stream) {
  const float* q      = (const float*)d_in[0];
  const float* fmap   = (const float*)d_in[1];
  const float* ref_xy = (const float*)d_in[2];
  const float* Wv     = (const float*)d_in[3];
  const float* W_off  = (const float*)d_in[4];
  const float* b_off  = (const float*)d_in[5];
  const float* W_w    = (const float*)d_in[6];
  const float* b_w    = (const float*)d_in[7];
  const float* W_out  = (const float*)d_in[8];
  const float* b_out  = (const float*)d_in[9];
  float* out = (float*)d_out;

  // workspace layout; vflat aliases qsplit (dead after proj_gemm)
  char* ws = (char*)d_ws;
  __hip_bfloat16* qsplit = (__hip_bfloat16*)ws;       // 8192*1024*2 = 16,777,216 B
  __hip_bfloat16* vflat  = (__hip_bfloat16*)ws;       // alias: 4*8*4096*64*2 = same size
  ws += 16777216;
  __hip_bfloat16* Wcat   = (__hip_bfloat16*)ws; ws += 384 * 1536 * 2;
  float* bias_cat        = (float*)ws;          ws += 384 * 4;
  float* projbuf         = (float*)ws;          ws += 8192 * 384 * 4;
  __hip_bfloat16* fmapT  = (__hip_bfloat16*)ws; ws += 8388608 * 2;
  __hip_bfloat16* WvT    = (__hip_bfloat16*)ws; ws += 262144 * 2;
  __hip_bfloat16* WoutT  = (__hip_bfloat16*)ws; ws += 262144 * 2;
  __hip_bfloat16* ctxb   = (__hip_bfloat16*)ws; ws += 4194304 * 2;

  // 1) prep: split q, build Wcat/bias, transposes
  split_q_kernel<<<dim3(8192 * 128 / 256), 256, 0, stream>>>(q, qsplit);
  prep_w_kernel<<<dim3((384 * 1536 + 255) / 256), 256, 0, stream>>>(
      W_off, W_w, b_off, b_w, Wcat, bias_cat);
  transpose_to_bf16<<<dim3(4096 / 32, 512 / 32, Bsz), 256, 0, stream>>>(fmap, fmapT, 512, 4096);
  transpose_to_bf16<<<dim3(512 / 32, 512 / 32, 1), 256, 0, stream>>>(Wv, WvT, 512, 512);
  transpose_to_bf16<<<dim3(512 / 32, 512 / 32, 1), 256, 0, stream>>>(W_out, WoutT, 512, 512);

  // 2) fused offset+logit projection, split-bf16 (fp32-accurate): N=384, K=1536
  mfma_gemm_bt<0, true><<<dim3(8192 / 128, 384 / 128, 1), 256, 0, stream>>>(
      qsplit, 1024, Wcat, 1536, bias_cat, projbuf, 8192, 1536, 384);

  // 3) value projection -> vflat bf16 (b,h,s,dh)   [overwrites qsplit alias]
  mfma_gemm_bt<1, false><<<dim3(4096 / 128, 512 / 128, Bsz), 256, 0, stream>>>(
      fmapT, 512, WvT, 512, nullptr, vflat, 4096, 512, 0);

  // 4) fused softmax + bilinear gather -> ctx bf16
  sample_kernel<<<dim3(Bsz * T), 256, 0, stream>>>(
      ref_xy, projbuf, (const unsigned int*)vflat, (unsigned int*)ctxb);

  // 5) output projection + bias -> fp32 out
  mfma_gemm_bt<0, false><<<dim3(8192 / 128, 512 / 128, 1), 256, 0, stream>>>(
      ctxb, 512, WoutT, 512, b_out, out, 8192, 512, 512);
}

// Round 4
// 234.834 us; speedup vs baseline: 1.9305x; 1.0648x over previous
//
#include <hip/hip_runtime.h>
#include <hip/hip_bf16.h>
#include <math.h>

// Problem constants
constexpr int Bsz = 4, T = 2048, Hh = 8;
constexpr int HFi = 64, WFi = 64;
constexpr float RADIUS = 0.08f;

typedef __bf16 bf16x8 __attribute__((ext_vector_type(8)));
typedef float f32x4 __attribute__((ext_vector_type(4)));

typedef const __attribute__((address_space(1))) void* gcptr;
typedef __attribute__((address_space(3))) void* lptr;

#define GLOAD_LDS16(g, l) \
  __builtin_amdgcn_global_load_lds((gcptr)(const void*)(g), (lptr)(void*)(l), 16, 0, 0)

// ---------------------------------------------------------------------------
// Tiled transpose + fp32->bf16 convert: in (R x C row-major) -> out (C x R).
// (used for fmap only; weight transposes are folded into prep_kernel)
// ---------------------------------------------------------------------------
__global__ __launch_bounds__(256) void transpose_to_bf16(
    const float* __restrict__ in, __hip_bfloat16* __restrict__ out,
    int R, int C) {
  __shared__ float tile[32][33];
  const size_t bo = (size_t)blockIdx.z * R * C;
  const int c0 = blockIdx.x * 32, r0 = blockIdx.y * 32;
  const int tx = threadIdx.x & 31, ty = threadIdx.x >> 5;
#pragma unroll
  for (int i = ty; i < 32; i += 8)
    tile[i][tx] = in[bo + (size_t)(r0 + i) * C + c0 + tx];
  __syncthreads();
#pragma unroll
  for (int i = ty; i < 32; i += 8)
    out[bo + (size_t)(c0 + i) * R + r0 + tx] = __float2bfloat16(tile[tx][i]);
}

// ---------------------------------------------------------------------------
// Combined prep kernel (saves 3 dispatches):
//  blocks [0,4096):    split q into hi/lo bf16 (qsplit[m][0:512]=hi,[512:1024]=lo)
//  blocks [4096,6400): build Wcat (384x1536 B^T = [W_hi|W_hi|W_lo]) + bias_cat
//  blocks [6400,6912): transpose Wv -> WvT, W_out -> WoutT (bf16, B^T layout)
// ---------------------------------------------------------------------------
__global__ __launch_bounds__(256) void prep_kernel(
    const float* __restrict__ q, __hip_bfloat16* __restrict__ qsplit,
    const float* __restrict__ W_off, const float* __restrict__ W_w,
    const float* __restrict__ b_off, const float* __restrict__ b_w,
    __hip_bfloat16* __restrict__ Wcat, float* __restrict__ bias_cat,
    const float* __restrict__ Wv, __hip_bfloat16* __restrict__ WvT,
    const float* __restrict__ W_out, __hip_bfloat16* __restrict__ WoutT) {
  __shared__ float tile[32][33];
  const int blk = blockIdx.x;
  if (blk < 4096) {
    const int idx = blk * 256 + threadIdx.x;  // 8192*128
    const int m = idx >> 7, kq = (idx & 127) * 4;
    float4 v = *(const float4*)&q[(size_t)m * 512 + kq];
    union { __hip_bfloat16 b[4]; ushort4 u; } hi, lo;
    float f[4] = {v.x, v.y, v.z, v.w};
#pragma unroll
    for (int i = 0; i < 4; ++i) {
      hi.b[i] = __float2bfloat16(f[i]);
      lo.b[i] = __float2bfloat16(f[i] - __bfloat162float(hi.b[i]));
    }
    *(ushort4*)&qsplit[(size_t)m * 1024 + kq] = hi.u;
    *(ushort4*)&qsplit[(size_t)m * 1024 + 512 + kq] = lo.u;
  } else if (blk < 6400) {
    const int idx = (blk - 4096) * 256 + threadIdx.x;  // 384*1536 = 589824
    const int n = idx / 1536, kp = idx % 1536;
    const int k = kp & 511;
    const float w = (n < 256) ? W_off[(size_t)k * 256 + n]
                              : W_w[(size_t)k * 128 + (n - 256)];
    const __hip_bfloat16 h = __float2bfloat16(w);
    const __hip_bfloat16 o =
        (kp < 1024) ? h : __float2bfloat16(w - __bfloat162float(h));
    Wcat[(size_t)n * 1536 + kp] = o;
    if (idx < 384) bias_cat[idx] = (idx < 256) ? b_off[idx] : b_w[idx - 256];
  } else {
    const int t2 = blk - 6400;  // 0..511
    const float* src = (t2 < 256) ? Wv : W_out;
    __hip_bfloat16* dst = (t2 < 256) ? WvT : WoutT;
    const int tl = t2 & 255;
    const int c0 = (tl & 15) * 32, r0 = (tl >> 4) * 32;
    const int tx = threadIdx.x & 31, ty = threadIdx.x >> 5;
#pragma unroll
    for (int i = ty; i < 32; i += 8)
      tile[i][tx] = src[(size_t)(r0 + i) * 512 + c0 + tx];
    __syncthreads();
#pragma unroll
    for (int i = ty; i < 32; i += 8)
      dst[(size_t)(c0 + i) * 512 + r0 + tx] = __float2bfloat16(tile[tx][i]);
  }
}

// ---------------------------------------------------------------------------
// bf16 MFMA GEMM, B^T layout: C[m][n] = sum_k A[m*lda+k] * Bm[n*ldb+k] (+bias)
// 128x128 tile, BK=64, global_load_lds(16B) staging (m97 structure).
// LDS tiles unpadded [128][64] bf16 (row = 128 B): instruction j of 16 covers
// rows [8j,8j+8); lane l -> row 8j + l/8, col elems (l%8)*8. Each wave issues
// j = wave*4 + i for i in 0..3.
// MODE 0: C fp32 row-major ldc, +bias.
// MODE 1: C bf16 scattered to vflat[((b*8+head)*4096+s)*64+dh].
// AWRAP: split-K GEMM; A k-index k0>=1024 reads A at k0-1024.
// ---------------------------------------------------------------------------
template <int MODE, bool AWRAP>
__global__ __launch_bounds__(256) void mfma_gemm_bt(
    const __hip_bfloat16* __restrict__ A, int lda,
    const __hip_bfloat16* __restrict__ Bm, int ldb,
    const float* __restrict__ bias, void* __restrict__ Cout,
    int M, int Kt, int ldc) {
  __shared__ unsigned short As[128 * 64];
  __shared__ unsigned short Bs[128 * 64];
  const int tid = threadIdx.x;
  const int lane = tid & 63;
  const int wave = tid >> 6;
  const int wm = (wave & 1) * 64, wn = (wave >> 1) * 64;
  const int l15 = lane & 15, quad = lane >> 4;
  const int m0 = blockIdx.x * 128, n0 = blockIdx.y * 128;
  const int b = blockIdx.z;
  const __hip_bfloat16* Ab = A + (size_t)b * M * lda;

  f32x4 acc[4][4] = {};

  const int srow = lane >> 3;        // 0..7
  const int scol = (lane & 7) * 8;   // element offset 0..56

  for (int k0 = 0; k0 < Kt; k0 += 64) {
    const int ka = AWRAP ? (k0 >= 1024 ? k0 - 1024 : k0) : k0;
#pragma unroll
    for (int i = 0; i < 4; ++i) {
      const int j = wave * 4 + i;        // chunk 0..15
      const int r = j * 8 + srow;        // row 0..127
      GLOAD_LDS16(Ab + (size_t)(m0 + r) * lda + ka + scol, As + j * 512);
      GLOAD_LDS16(Bm + (size_t)(n0 + r) * ldb + k0 + scol, Bs + j * 512);
    }
    __syncthreads();
#pragma unroll
    for (int ks = 0; ks < 2; ++ks) {
      bf16x8 af[4], bfr[4];
#pragma unroll
      for (int i = 0; i < 4; ++i)
        af[i] = *(const bf16x8*)&As[(wm + i * 16 + l15) * 64 + ks * 32 + quad * 8];
#pragma unroll
      for (int j = 0; j < 4; ++j)
        bfr[j] = *(const bf16x8*)&Bs[(wn + j * 16 + l15) * 64 + ks * 32 + quad * 8];
#pragma unroll
      for (int i = 0; i < 4; ++i)
#pragma unroll
        for (int j = 0; j < 4; ++j)
          acc[i][j] = __builtin_amdgcn_mfma_f32_16x16x32_bf16(af[i], bfr[j], acc[i][j], 0, 0, 0);
    }
    __syncthreads();
  }

  if (MODE == 0) {
    float* C = (float*)Cout;
#pragma unroll
    for (int i = 0; i < 4; ++i) {
      const int mbase = m0 + wm + i * 16 + quad * 4;
#pragma unroll
      for (int j = 0; j < 4; ++j) {
        const int n = n0 + wn + j * 16 + l15;
        const float bb = bias[n];
#pragma unroll
        for (int r = 0; r < 4; ++r)
          C[(size_t)(mbase + r) * ldc + n] = acc[i][j][r] + bb;
      }
    }
  } else {
    __hip_bfloat16* C = (__hip_bfloat16*)Cout + (size_t)b * 8 * 4096 * 64;
#pragma unroll
    for (int i = 0; i < 4; ++i) {
      const int mbase = m0 + wm + i * 16 + quad * 4;  // spatial index s
#pragma unroll
      for (int j = 0; j < 4; ++j) {
        const int ng = n0 + wn + j * 16 + l15;
        const int head = ng >> 6, dh = ng & 63;
#pragma unroll
        for (int r = 0; r < 4; ++r)
          C[(size_t)head * (4096 * 64) + (size_t)(mbase + r) * 64 + dh] =
              __float2bfloat16(acc[i][j][r]);
      }
    }
  }
}

// ---------------------------------------------------------------------------
// Fused softmax + bilinear sampling, dh-pair packed, register-only softmax.
// Block = (b,t), 4 waves; wave handles heads {w, w+4}.
// Lanes 0..31: points 0..7, lanes 32..63: points 8..15; lane k covers dh pair
// (2k,2k+1) via uint loads of bf16 vflat. Halves combined with shfl_xor(32).
// Softmax: each half reduces its 8 logits held in two float4s (registers —
// avoids PromoteAlloca->LDS bank conflicts seen in round 3), cross-half via
// shfl_xor(32) of max and sum.
// ---------------------------------------------------------------------------
__global__ __launch_bounds__(256) void sample_kernel(
    const float* __restrict__ ref_xy, const float* __restrict__ projbuf,
    const unsigned int* __restrict__ vflat2, unsigned int* __restrict__ ctx2) {
  const int bt = blockIdx.x;
  const int b = bt >> 11;  // T = 2048
  const int wave = threadIdx.x >> 6;
  const int lane = threadIdx.x & 63;
  const int l31 = lane & 31;
  const bool hiHalf = lane >= 32;

  const float ref_x = ref_xy[bt * 2 + 0];
  const float ref_y = ref_xy[bt * 2 + 1];
  const float* prow = projbuf + (size_t)bt * 384;

  for (int h = wave; h < Hh; h += 4) {
    // 8 logits for this half, in registers
    const float* lg = prow + 256 + h * 16 + (hiHalf ? 8 : 0);
    float4 ea = *(const float4*)lg;
    float4 eb = *(const float4*)(lg + 4);
    float mh = fmaxf(fmaxf(fmaxf(ea.x, ea.y), fmaxf(ea.z, ea.w)),
                     fmaxf(fmaxf(eb.x, eb.y), fmaxf(eb.z, eb.w)));
    const float mx = fmaxf(mh, __shfl_xor(mh, 32, 64));
    ea.x = __expf(ea.x - mx); ea.y = __expf(ea.y - mx);
    ea.z = __expf(ea.z - mx); ea.w = __expf(ea.w - mx);
    eb.x = __expf(eb.x - mx); eb.y = __expf(eb.y - mx);
    eb.z = __expf(eb.z - mx); eb.w = __expf(eb.w - mx);
    const float sh = ea.x + ea.y + ea.z + ea.w + eb.x + eb.y + eb.z + eb.w;
    const float inv = 1.0f / (sh + __shfl_xor(sh, 32, 64));

    const float* of = prow + h * 32 + (hiHalf ? 16 : 0);
    const unsigned int* vb = vflat2 + (size_t)(b * 8 + h) * (4096 * 32) + l31;

    float acc0 = 0.f, acc1 = 0.f;
#pragma unroll
    for (int pp = 0; pp < 8; ++pp) {
      const float ep = (pp == 0) ? ea.x : (pp == 1) ? ea.y : (pp == 2) ? ea.z
                     : (pp == 3) ? ea.w : (pp == 4) ? eb.x : (pp == 5) ? eb.y
                     : (pp == 6) ? eb.z : eb.w;
      const float aw = inv * ep;
      const float2 o2 = *(const float2*)&of[pp * 2];
      const float ix = (ref_x + RADIUS * o2.x) * (float)(WFi - 1);
      const float iy = (ref_y + RADIUS * o2.y) * (float)(HFi - 1);
      const float ix0f = floorf(ix), iy0f = floorf(iy);
      const float fx = ix - ix0f, fy = iy - iy0f;
      const int ix0 = (int)ix0f, iy0 = (int)iy0f;

      float wx0 = 1.f - fx, wx1 = fx;
      float wy0 = 1.f - fy, wy1 = fy;
      if (ix0 == -1) { wx0 = fx; wx1 = 0.f; }
      if (ix0 == 63) { wx0 = 0.f; wx1 = 1.f - fx; }
      if (ix0 < -1 || ix0 > 63) { wx0 = 0.f; wx1 = 0.f; }
      if (iy0 == -1) { wy0 = fy; wy1 = 0.f; }
      if (iy0 == 63) { wy0 = 0.f; wy1 = 1.f - fy; }
      if (iy0 < -1 || iy0 > 63) { wy0 = 0.f; wy1 = 0.f; }
      const int xA = min(max(ix0, 0), WFi - 2);
      const int yA = min(max(iy0, 0), HFi - 2);

      wy0 *= aw;
      wy1 *= aw;
      const float w00 = wx0 * wy0, w10 = wx1 * wy0;
      const float w01 = wx0 * wy1, w11 = wx1 * wy1;

      const unsigned int* r0 = vb + (size_t)(yA * WFi + xA) * 32;
      const unsigned int* r1 = r0 + WFi * 32;
      const unsigned int v00 = r0[0], v10 = r0[32];
      const unsigned int v01 = r1[0], v11 = r1[32];

      const float e00 = __uint_as_float(v00 << 16), o00 = __uint_as_float(v00 & 0xffff0000u);
      const float e10 = __uint_as_float(v10 << 16), o10 = __uint_as_float(v10 & 0xffff0000u);
      const float e01 = __uint_as_float(v01 << 16), o01 = __uint_as_float(v01 & 0xffff0000u);
      const float e11 = __uint_as_float(v11 << 16), o11 = __uint_as_float(v11 & 0xffff0000u);

      acc0 = fmaf(w00, e00, acc0);
      acc1 = fmaf(w00, o00, acc1);
      acc0 = fmaf(w10, e10, acc0);
      acc1 = fmaf(w10, o10, acc1);
      acc0 = fmaf(w01, e01, acc0);
      acc1 = fmaf(w01, o01, acc1);
      acc0 = fmaf(w11, e11, acc0);
      acc1 = fmaf(w11, o11, acc1);
    }

    acc0 += __shfl_xor(acc0, 32, 64);
    acc1 += __shfl_xor(acc1, 32, 64);
    if (!hiHalf) {
      union { __hip_bfloat16 b; unsigned short u; } c0, c1;
      c0.b = __float2bfloat16(acc0);
      c1.b = __float2bfloat16(acc1);
      ctx2[(size_t)bt * 256 + h * 32 + l31] = ((unsigned int)c1.u << 16) | c0.u;
    }
  }
}

// ---------------------------------------------------------------------------
extern "C" void kernel_launch(void* const* d_in, const int* in_sizes, int n_in,
                              void* d_out, int out_size, void* d_ws, size_t ws_size,
                              hipStream_t stream) {
  const float* q      = (const float*)d_in[0];
  const float* fmap   = (const float*)d_in[1];
  const float* ref_xy = (const float*)d_in[2];
  const float* Wv     = (const float*)d_in[3];
  const float* W_off  = (const float*)d_in[4];
  const float* b_off  = (const float*)d_in[5];
  const float* W_w    = (const float*)d_in[6];
  const float* b_w    = (const float*)d_in[7];
  const float* W_out  = (const float*)d_in[8];
  const float* b_out  = (const float*)d_in[9];
  float* out = (float*)d_out;

  // workspace layout; vflat aliases qsplit (dead after proj_gemm)
  char* ws = (char*)d_ws;
  __hip_bfloat16* qsplit = (__hip_bfloat16*)ws;       // 8192*1024*2 = 16,777,216 B
  __hip_bfloat16* vflat  = (__hip_bfloat16*)ws;       // alias, same size
  ws += 16777216;
  __hip_bfloat16* Wcat   = (__hip_bfloat16*)ws; ws += 384 * 1536 * 2;
  float* bias_cat        = (float*)ws;          ws += 384 * 4;
  float* projbuf         = (float*)ws;          ws += 8192 * 384 * 4;
  __hip_bfloat16* fmapT  = (__hip_bfloat16*)ws; ws += 8388608 * 2;
  __hip_bfloat16* WvT    = (__hip_bfloat16*)ws; ws += 262144 * 2;
  __hip_bfloat16* WoutT  = (__hip_bfloat16*)ws; ws += 262144 * 2;
  __hip_bfloat16* ctxb   = (__hip_bfloat16*)ws; ws += 4194304 * 2;

  // 1) fused prep: split q, build Wcat/bias, weight transposes
  prep_kernel<<<dim3(6912), 256, 0, stream>>>(
      q, qsplit, W_off, W_w, b_off, b_w, Wcat, bias_cat, Wv, WvT, W_out, WoutT);
  transpose_to_bf16<<<dim3(4096 / 32, 512 / 32, Bsz), 256, 0, stream>>>(fmap, fmapT, 512, 4096);

  // 2) fused offset+logit projection, split-bf16 (fp32-accurate): N=384, K=1536
  mfma_gemm_bt<0, true><<<dim3(8192 / 128, 384 / 128, 1), 256, 0, stream>>>(
      qsplit, 1024, Wcat, 1536, bias_cat, projbuf, 8192, 1536, 384);

  // 3) value projection -> vflat bf16 (b,h,s,dh)   [overwrites qsplit alias]
  mfma_gemm_bt<1, false><<<dim3(4096 / 128, 512 / 128, Bsz), 256, 0, stream>>>(
      fmapT, 512, WvT, 512, nullptr, vflat, 4096, 512, 0);

  // 4) fused softmax + bilinear gather -> ctx bf16
  sample_kernel<<<dim3(Bsz * T), 256, 0, stream>>>(
      ref_xy, projbuf, (const unsigned int*)vflat, (unsigned int*)ctxb);

  // 5) output projection + bias -> fp32 out
  mfma_gemm_bt<0, false><<<dim3(8192 / 128, 512 / 128, 1), 256, 0, stream>>>(
      ctxb, 512, WoutT, 512, b_out, out, 8192, 512, 512);
}

// Round 5
// 229.854 us; speedup vs baseline: 1.9723x; 1.0217x over previous
//
#include <hip/hip_runtime.h>
#include <hip/hip_bf16.h>
#include <hip/hip_fp16.h>
#include <math.h>

// Problem constants
constexpr int Bsz = 4, T = 2048, Hh = 8;
constexpr int HFi = 64, WFi = 64;
constexpr float RADIUS = 0.08f;

typedef __bf16 bf16x8 __attribute__((ext_vector_type(8)));
typedef float f32x4 __attribute__((ext_vector_type(4)));

typedef const __attribute__((address_space(1))) void* gcptr;
typedef __attribute__((address_space(3))) void* lptr;

#define GLOAD_LDS16(g, l) \
  __builtin_amdgcn_global_load_lds((gcptr)(const void*)(g), (lptr)(void*)(l), 16, 0, 0)

// ---------------------------------------------------------------------------
// Combined prep kernel (one dispatch for all input conditioning):
//  blocks [0,4096):        split q into hi/lo bf16 (qsplit[m][0:512]=hi,[512:1024]=lo)
//  blocks [4096,6400):     build Wcat (384x1536 B^T = [W_hi|W_hi|W_lo]) + bias_cat
//  blocks [6400,6912):     transpose Wv -> WvT, W_out -> WoutT (bf16, B^T)
//  blocks [6912,15104):    transpose fmap (B,512,4096) -> fmapT (B,4096,512) bf16
// ---------------------------------------------------------------------------
__global__ __launch_bounds__(256) void prep_kernel(
    const float* __restrict__ q, __hip_bfloat16* __restrict__ qsplit,
    const float* __restrict__ W_off, const float* __restrict__ W_w,
    const float* __restrict__ b_off, const float* __restrict__ b_w,
    __hip_bfloat16* __restrict__ Wcat, float* __restrict__ bias_cat,
    const float* __restrict__ Wv, __hip_bfloat16* __restrict__ WvT,
    const float* __restrict__ W_out, __hip_bfloat16* __restrict__ WoutT,
    const float* __restrict__ fmap, __hip_bfloat16* __restrict__ fmapT) {
  __shared__ float tile[32][33];
  const int blk = blockIdx.x;
  if (blk < 4096) {
    const int idx = blk * 256 + threadIdx.x;  // 8192*128
    const int m = idx >> 7, kq = (idx & 127) * 4;
    float4 v = *(const float4*)&q[(size_t)m * 512 + kq];
    union { __hip_bfloat16 b[4]; ushort4 u; } hi, lo;
    float f[4] = {v.x, v.y, v.z, v.w};
#pragma unroll
    for (int i = 0; i < 4; ++i) {
      hi.b[i] = __float2bfloat16(f[i]);
      lo.b[i] = __float2bfloat16(f[i] - __bfloat162float(hi.b[i]));
    }
    *(ushort4*)&qsplit[(size_t)m * 1024 + kq] = hi.u;
    *(ushort4*)&qsplit[(size_t)m * 1024 + 512 + kq] = lo.u;
  } else if (blk < 6400) {
    const int idx = (blk - 4096) * 256 + threadIdx.x;  // 384*1536 = 589824
    const int n = idx / 1536, kp = idx % 1536;
    const int k = kp & 511;
    const float w = (n < 256) ? W_off[(size_t)k * 256 + n]
                              : W_w[(size_t)k * 128 + (n - 256)];
    const __hip_bfloat16 h = __float2bfloat16(w);
    const __hip_bfloat16 o =
        (kp < 1024) ? h : __float2bfloat16(w - __bfloat162float(h));
    Wcat[(size_t)n * 1536 + kp] = o;
    if (idx < 384) bias_cat[idx] = (idx < 256) ? b_off[idx] : b_w[idx - 256];
  } else if (blk < 6912) {
    const int t2 = blk - 6400;  // 0..511
    const float* src = (t2 < 256) ? Wv : W_out;
    __hip_bfloat16* dst = (t2 < 256) ? WvT : WoutT;
    const int tl = t2 & 255;
    const int c0 = (tl & 15) * 32, r0 = (tl >> 4) * 32;
    const int tx = threadIdx.x & 31, ty = threadIdx.x >> 5;
#pragma unroll
    for (int i = ty; i < 32; i += 8)
      tile[i][tx] = src[(size_t)(r0 + i) * 512 + c0 + tx];
    __syncthreads();
#pragma unroll
    for (int i = ty; i < 32; i += 8)
      dst[(size_t)(c0 + i) * 512 + r0 + tx] = __float2bfloat16(tile[tx][i]);
  } else {
    const int t3 = blk - 6912;          // 0..8191
    const int b = t3 >> 11;             // 2048 tiles per batch
    const int tl = t3 & 2047;
    const int c0 = (tl & 127) * 32;     // spatial col 0..4064
    const int r0 = (tl >> 7) * 32;      // channel row 0..480
    const float* src = fmap + (size_t)b * 512 * 4096;
    __hip_bfloat16* dst = fmapT + (size_t)b * 4096 * 512;
    const int tx = threadIdx.x & 31, ty = threadIdx.x >> 5;
#pragma unroll
    for (int i = ty; i < 32; i += 8)
      tile[i][tx] = src[(size_t)(r0 + i) * 4096 + c0 + tx];
    __syncthreads();
#pragma unroll
    for (int i = ty; i < 32; i += 8)
      dst[(size_t)(c0 + i) * 512 + r0 + tx] = __float2bfloat16(tile[tx][i]);
  }
}

// ---------------------------------------------------------------------------
// bf16 MFMA GEMM, B^T layout: C[m][n] = sum_k A[m*lda+k] * Bm[n*ldb+k] (+bias)
// 128x128 tile, BK=64, global_load_lds(16B) staging (m97 structure).
// MODE 0: C fp32 row-major ldc, +bias.
// MODE 1: C bf16 scattered to vflat[((b*8+head)*4096+s)*64+dh].
// AWRAP: split-K GEMM; A k-index k0>=1024 reads A at k0-1024.
// ---------------------------------------------------------------------------
template <int MODE, bool AWRAP>
__global__ __launch_bounds__(256) void mfma_gemm_bt(
    const __hip_bfloat16* __restrict__ A, int lda,
    const __hip_bfloat16* __restrict__ Bm, int ldb,
    const float* __restrict__ bias, void* __restrict__ Cout,
    int M, int Kt, int ldc) {
  __shared__ unsigned short As[128 * 64];
  __shared__ unsigned short Bs[128 * 64];
  const int tid = threadIdx.x;
  const int lane = tid & 63;
  const int wave = tid >> 6;
  const int wm = (wave & 1) * 64, wn = (wave >> 1) * 64;
  const int l15 = lane & 15, quad = lane >> 4;
  const int m0 = blockIdx.x * 128, n0 = blockIdx.y * 128;
  const int b = blockIdx.z;
  const __hip_bfloat16* Ab = A + (size_t)b * M * lda;

  f32x4 acc[4][4] = {};

  const int srow = lane >> 3;        // 0..7
  const int scol = (lane & 7) * 8;   // element offset 0..56

  for (int k0 = 0; k0 < Kt; k0 += 64) {
    const int ka = AWRAP ? (k0 >= 1024 ? k0 - 1024 : k0) : k0;
#pragma unroll
    for (int i = 0; i < 4; ++i) {
      const int j = wave * 4 + i;        // chunk 0..15
      const int r = j * 8 + srow;        // row 0..127
      GLOAD_LDS16(Ab + (size_t)(m0 + r) * lda + ka + scol, As + j * 512);
      GLOAD_LDS16(Bm + (size_t)(n0 + r) * ldb + k0 + scol, Bs + j * 512);
    }
    __syncthreads();
#pragma unroll
    for (int ks = 0; ks < 2; ++ks) {
      bf16x8 af[4], bfr[4];
#pragma unroll
      for (int i = 0; i < 4; ++i)
        af[i] = *(const bf16x8*)&As[(wm + i * 16 + l15) * 64 + ks * 32 + quad * 8];
#pragma unroll
      for (int j = 0; j < 4; ++j)
        bfr[j] = *(const bf16x8*)&Bs[(wn + j * 16 + l15) * 64 + ks * 32 + quad * 8];
#pragma unroll
      for (int i = 0; i < 4; ++i)
#pragma unroll
        for (int j = 0; j < 4; ++j)
          acc[i][j] = __builtin_amdgcn_mfma_f32_16x16x32_bf16(af[i], bfr[j], acc[i][j], 0, 0, 0);
    }
    __syncthreads();
  }

  if (MODE == 0) {
    float* C = (float*)Cout;
#pragma unroll
    for (int i = 0; i < 4; ++i) {
      const int mbase = m0 + wm + i * 16 + quad * 4;
#pragma unroll
      for (int j = 0; j < 4; ++j) {
        const int n = n0 + wn + j * 16 + l15;
        const float bb = bias[n];
#pragma unroll
        for (int r = 0; r < 4; ++r)
          C[(size_t)(mbase + r) * ldc + n] = acc[i][j][r] + bb;
      }
    }
  } else {
    __hip_bfloat16* C = (__hip_bfloat16*)Cout + (size_t)b * 8 * 4096 * 64;
#pragma unroll
    for (int i = 0; i < 4; ++i) {
      const int mbase = m0 + wm + i * 16 + quad * 4;  // spatial index s
#pragma unroll
      for (int j = 0; j < 4; ++j) {
        const int ng = n0 + wn + j * 16 + l15;
        const int head = ng >> 6, dh = ng & 63;
#pragma unroll
        for (int r = 0; r < 4; ++r)
          C[(size_t)head * (4096 * 64) + (size_t)(mbase + r) * 64 + dh] =
              __float2bfloat16(acc[i][j][r]);
      }
    }
  }
}

// ---------------------------------------------------------------------------
// Weight precompute: one thread per (bt, h). Softmax over 16 logits + per-point
// position math, emitting packed float4 per point:
//   .x = bitcast(half2(wx0, wx1)), .y = wy0*aw, .z = wy1*aw,
//   .w = bitcast(int base) with base = (yA*64 + xA) * 32 (dword index, exact)
// ---------------------------------------------------------------------------
__global__ __launch_bounds__(256) void wprep_kernel(
    const float* __restrict__ ref_xy, const float* __restrict__ projbuf,
    float4* __restrict__ wbuf) {
  const int idx = blockIdx.x * 256 + threadIdx.x;  // bt*8 + h, 65536 total
  const int bt = idx >> 3, h = idx & 7;
  const float ref_x = ref_xy[bt * 2 + 0];
  const float ref_y = ref_xy[bt * 2 + 1];
  const float* prow = projbuf + (size_t)bt * 384;
  const float* lg = prow + 256 + h * 16;

  float lv[16];
  float mx = -1e30f;
#pragma unroll
  for (int p = 0; p < 16; ++p) {
    lv[p] = lg[p];
    mx = fmaxf(mx, lv[p]);
  }
  float sum = 0.f;
#pragma unroll
  for (int p = 0; p < 16; ++p) {
    lv[p] = __expf(lv[p] - mx);
    sum += lv[p];
  }
  const float inv = 1.0f / sum;

  const float* of = prow + h * 32;
  float4* wout = wbuf + (size_t)idx * 16;
#pragma unroll
  for (int p = 0; p < 16; ++p) {
    const float aw = inv * lv[p];
    const float2 o2 = *(const float2*)&of[p * 2];
    const float ix = (ref_x + RADIUS * o2.x) * (float)(WFi - 1);
    const float iy = (ref_y + RADIUS * o2.y) * (float)(HFi - 1);
    const float ix0f = floorf(ix), iy0f = floorf(iy);
    const float fx = ix - ix0f, fy = iy - iy0f;
    const int ix0 = (int)ix0f, iy0 = (int)iy0f;

    float wx0 = 1.f - fx, wx1 = fx;
    float wy0 = 1.f - fy, wy1 = fy;
    if (ix0 == -1) { wx0 = fx; wx1 = 0.f; }
    if (ix0 == 63) { wx0 = 0.f; wx1 = 1.f - fx; }
    if (ix0 < -1 || ix0 > 63) { wx0 = 0.f; wx1 = 0.f; }
    if (iy0 == -1) { wy0 = fy; wy1 = 0.f; }
    if (iy0 == 63) { wy0 = 0.f; wy1 = 1.f - fy; }
    if (iy0 < -1 || iy0 > 63) { wy0 = 0.f; wy1 = 0.f; }
    const int xA = min(max(ix0, 0), WFi - 2);
    const int yA = min(max(iy0, 0), HFi - 2);

    union { __half2 h2; float f; } ux;
    ux.h2 = __floats2half2_rn(wx0, wx1);
    union { int i; float f; } ub;
    ub.i = (yA * WFi + xA) * 32;
    wout[p] = make_float4(ux.f, wy0 * aw, wy1 * aw, ub.f);
  }
}

// ---------------------------------------------------------------------------
// Bilinear gather with precomputed weights. Block = (b,t) via XCD swizzle,
// 4 waves; wave handles heads {w, w+4}. Lanes 0..31: points 0..7, lanes
// 32..63: points 8..15; lane covers dh pair (2k,2k+1) via uint loads of bf16
// vflat. Halves combined with shfl_xor(32).
// ---------------------------------------------------------------------------
__global__ __launch_bounds__(256) void sample_kernel(
    const float4* __restrict__ wbuf, const unsigned int* __restrict__ vflat2,
    unsigned int* __restrict__ ctx2) {
  // XCD swizzle: consecutive blocks go to different XCDs (dispatch %8
  // heuristic); give each XCD a contiguous bt range -> single-b vflat reuse
  // in its 4 MB L2.
  const int blk = blockIdx.x;
  const int bt = (blk & 7) * 1024 + (blk >> 3);
  const int b = bt >> 11;  // T = 2048
  const int wave = threadIdx.x >> 6;
  const int lane = threadIdx.x & 63;
  const int l31 = lane & 31;
  const bool hiHalf = lane >= 32;

  for (int h = wave; h < Hh; h += 4) {
    const float4* wq = wbuf + ((size_t)bt * 8 + h) * 16 + (hiHalf ? 8 : 0);
    const unsigned int* vb = vflat2 + (size_t)(b * 8 + h) * (4096 * 32) + l31;

    float acc0 = 0.f, acc1 = 0.f;
#pragma unroll
    for (int pp = 0; pp < 8; ++pp) {
      const float4 w4 = wq[pp];
      union { float f; __half2 h2; } ux;
      ux.f = w4.x;
      const float wx0 = __low2float(ux.h2);
      const float wx1 = __high2float(ux.h2);
      union { float f; int i; } ub;
      ub.f = w4.w;
      const unsigned int* r0 = vb + ub.i;

      const unsigned int v00 = r0[0], v10 = r0[32];
      const unsigned int v01 = r0[2048], v11 = r0[2080];

      const float w00 = wx0 * w4.y, w10 = wx1 * w4.y;
      const float w01 = wx0 * w4.z, w11 = wx1 * w4.z;

      const float e00 = __uint_as_float(v00 << 16), o00 = __uint_as_float(v00 & 0xffff0000u);
      const float e10 = __uint_as_float(v10 << 16), o10 = __uint_as_float(v10 & 0xffff0000u);
      const float e01 = __uint_as_float(v01 << 16), o01 = __uint_as_float(v01 & 0xffff0000u);
      const float e11 = __uint_as_float(v11 << 16), o11 = __uint_as_float(v11 & 0xffff0000u);

      acc0 = fmaf(w00, e00, acc0);
      acc1 = fmaf(w00, o00, acc1);
      acc0 = fmaf(w10, e10, acc0);
      acc1 = fmaf(w10, o10, acc1);
      acc0 = fmaf(w01, e01, acc0);
      acc1 = fmaf(w01, o01, acc1);
      acc0 = fmaf(w11, e11, acc0);
      acc1 = fmaf(w11, o11, acc1);
    }

    acc0 += __shfl_xor(acc0, 32, 64);
    acc1 += __shfl_xor(acc1, 32, 64);
    if (!hiHalf) {
      union { __hip_bfloat16 b; unsigned short u; } c0, c1;
      c0.b = __float2bfloat16(acc0);
      c1.b = __float2bfloat16(acc1);
      ctx2[(size_t)bt * 256 + h * 32 + l31] = ((unsigned int)c1.u << 16) | c0.u;
    }
  }
}

// ---------------------------------------------------------------------------
extern "C" void kernel_launch(void* const* d_in, const int* in_sizes, int n_in,
                              void* d_out, int out_size, void* d_ws, size_t ws_size,
                              hipStream_t stream) {
  const float* q      = (const float*)d_in[0];
  const float* fmap   = (const float*)d_in[1];
  const float* ref_xy = (const float*)d_in[2];
  const float* Wv     = (const float*)d_in[3];
  const float* W_off  = (const float*)d_in[4];
  const float* b_off  = (const float*)d_in[5];
  const float* W_w    = (const float*)d_in[6];
  const float* b_w    = (const float*)d_in[7];
  const float* W_out  = (const float*)d_in[8];
  const float* b_out  = (const float*)d_in[9];
  float* out = (float*)d_out;

  // workspace; aliases: vflat<-qsplit (dead after proj GEMM),
  // wbuf<-fmapT+WvT (dead after vproj GEMM)
  char* ws = (char*)d_ws;
  __hip_bfloat16* qsplit = (__hip_bfloat16*)ws;       // 16,777,216 B
  __hip_bfloat16* vflat  = (__hip_bfloat16*)ws;       // alias, same size
  ws += 16777216;
  __hip_bfloat16* Wcat   = (__hip_bfloat16*)ws; ws += 384 * 1536 * 2;
  float* bias_cat        = (float*)ws;          ws += 384 * 4;
  float* projbuf         = (float*)ws;          ws += 8192 * 384 * 4;
  __hip_bfloat16* fmapT  = (__hip_bfloat16*)ws;       // 16,777,216 B
  float4* wbuf           = (float4*)ws;               // alias: 65536*16*16 = 16,777,216 B
  ws += 8388608 * 2;
  __hip_bfloat16* WvT    = (__hip_bfloat16*)ws; ws += 262144 * 2;
  __hip_bfloat16* WoutT  = (__hip_bfloat16*)ws; ws += 262144 * 2;
  __hip_bfloat16* ctxb   = (__hip_bfloat16*)ws; ws += 4194304 * 2;

  // 1) fused prep: split q, Wcat/bias, weight transposes, fmap transpose
  prep_kernel<<<dim3(15104), 256, 0, stream>>>(
      q, qsplit, W_off, W_w, b_off, b_w, Wcat, bias_cat, Wv, WvT, W_out, WoutT,
      fmap, fmapT);

  // 2) fused offset+logit projection, split-bf16 (fp32-accurate): N=384, K=1536
  mfma_gemm_bt<0, true><<<dim3(8192 / 128, 384 / 128, 1), 256, 0, stream>>>(
      qsplit, 1024, Wcat, 1536, bias_cat, projbuf, 8192, 1536, 384);

  // 3) value projection -> vflat bf16 (b,h,s,dh)   [overwrites qsplit alias]
  mfma_gemm_bt<1, false><<<dim3(4096 / 128, 512 / 128, Bsz), 256, 0, stream>>>(
      fmapT, 512, WvT, 512, nullptr, vflat, 4096, 512, 0);

  // 4) softmax + position math -> packed weights  [overwrites fmapT alias]
  wprep_kernel<<<dim3(65536 / 256), 256, 0, stream>>>(ref_xy, projbuf, wbuf);

  // 5) bilinear gather -> ctx bf16
  sample_kernel<<<dim3(Bsz * T), 256, 0, stream>>>(
      wbuf, (const unsigned int*)vflat, (unsigned int*)ctxb);

  // 6) output projection + bias -> fp32 out
  mfma_gemm_bt<0, false><<<dim3(8192 / 128, 512 / 128, 1), 256, 0, stream>>>(
      ctxb, 512, WoutT, 512, b_out, out, 8192, 512, 512);
}

// Round 6
// 200.379 us; speedup vs baseline: 2.2625x; 1.1471x over previous
//
#include <hip/hip_runtime.h>
#include <hip/hip_bf16.h>
#include <math.h>

// Problem constants
constexpr int Bsz = 4, T = 2048, Hh = 8;
constexpr int HFi = 64, WFi = 64;
constexpr float RADIUS = 0.08f;

typedef __bf16 bf16x8 __attribute__((ext_vector_type(8)));
typedef float f32x4 __attribute__((ext_vector_type(4)));
typedef unsigned short u16x8 __attribute__((ext_vector_type(8)));

typedef const __attribute__((address_space(1))) void* gcptr;
typedef __attribute__((address_space(3))) void* lptr;

#define GLOAD_LDS16(g, l) \
  __builtin_amdgcn_global_load_lds((gcptr)(const void*)(g), (lptr)(void*)(l), 16, 0, 0)

union BU { __hip_bfloat16 b; unsigned short u; };

// ---------------------------------------------------------------------------
// Combined prep kernel (one dispatch for all input conditioning):
//  blocks [0,4096):     split q into hi/lo bf16 (qsplit[m][0:512]=hi,[512:1024]=lo)
//  blocks [4096,6400):  build Wcat (384x1536 B^T = [W_hi|W_hi|W_lo]) + bias_cat
//  blocks [6400,6528):  transpose Wv -> WvT, W_out -> WoutT (64x64 tiles)
//  blocks [6528,8576):  transpose fmap (B,512,4096) -> fmapT (B,4096,512) bf16
// 64x64 transpose: fp32 LDS tile stride 65 (odd => 2-way bank aliasing only),
// scalar ds_writes, 16B-vector bf16 global stores (16 bf16 per thread-row).
// ---------------------------------------------------------------------------
__global__ __launch_bounds__(256) void prep_kernel(
    const float* __restrict__ q, __hip_bfloat16* __restrict__ qsplit,
    const float* __restrict__ W_off, const float* __restrict__ W_w,
    const float* __restrict__ b_off, const float* __restrict__ b_w,
    __hip_bfloat16* __restrict__ Wcat, float* __restrict__ bias_cat,
    const float* __restrict__ Wv, __hip_bfloat16* __restrict__ WvT,
    const float* __restrict__ W_out, __hip_bfloat16* __restrict__ WoutT,
    const float* __restrict__ fmap, __hip_bfloat16* __restrict__ fmapT) {
  __shared__ float tile[64][65];
  const int blk = blockIdx.x;
  const int tid = threadIdx.x;
  if (blk < 4096) {
    const int idx = blk * 256 + tid;  // 8192*128
    const int m = idx >> 7, kq = (idx & 127) * 4;
    float4 v = *(const float4*)&q[(size_t)m * 512 + kq];
    union { __hip_bfloat16 b[4]; ushort4 u; } hi, lo;
    float f[4] = {v.x, v.y, v.z, v.w};
#pragma unroll
    for (int i = 0; i < 4; ++i) {
      hi.b[i] = __float2bfloat16(f[i]);
      lo.b[i] = __float2bfloat16(f[i] - __bfloat162float(hi.b[i]));
    }
    *(ushort4*)&qsplit[(size_t)m * 1024 + kq] = hi.u;
    *(ushort4*)&qsplit[(size_t)m * 1024 + 512 + kq] = lo.u;
    return;
  }
  if (blk < 6400) {
    const int idx = (blk - 4096) * 256 + tid;  // 384*1536 = 589824
    const int n = idx / 1536, kp = idx % 1536;
    const int k = kp & 511;
    const float w = (n < 256) ? W_off[(size_t)k * 256 + n]
                              : W_w[(size_t)k * 128 + (n - 256)];
    const __hip_bfloat16 h = __float2bfloat16(w);
    const __hip_bfloat16 o =
        (kp < 1024) ? h : __float2bfloat16(w - __bfloat162float(h));
    Wcat[(size_t)n * 1536 + kp] = o;
    if (idx < 384) bias_cat[idx] = (idx < 256) ? b_off[idx] : b_w[idx - 256];
    return;
  }
  // --- 64x64 transpose segments ---
  const float* src;
  __hip_bfloat16* dst;
  int ldin, ldout, r0, c0;
  if (blk < 6528) {
    const int t2 = blk - 6400;  // 0..127
    src = (t2 < 64) ? Wv : W_out;
    dst = (t2 < 64) ? WvT : WoutT;
    ldin = 512; ldout = 512;
    const int tl = t2 & 63;
    r0 = (tl >> 3) * 64; c0 = (tl & 7) * 64;
  } else {
    const int t3 = blk - 6528;          // 0..2047
    const int b = t3 >> 9;              // 512 tiles per batch
    const int tl = t3 & 511;
    r0 = (tl >> 6) * 64;                // channel rows
    c0 = (tl & 63) * 64;                // spatial cols
    src = fmap + (size_t)b * 512 * 4096;
    dst = fmapT + (size_t)b * 4096 * 512;
    ldin = 4096; ldout = 512;
  }
  {
    const int tr = tid >> 2;          // 0..63 input row
    const int tc = (tid & 3) * 16;    // input col chunk
    const float* s = &src[(size_t)(r0 + tr) * ldin + c0 + tc];
#pragma unroll
    for (int j4 = 0; j4 < 4; ++j4) {
      float4 v = *(const float4*)&s[j4 * 4];
      tile[tr][tc + j4 * 4 + 0] = v.x;
      tile[tr][tc + j4 * 4 + 1] = v.y;
      tile[tr][tc + j4 * 4 + 2] = v.z;
      tile[tr][tc + j4 * 4 + 3] = v.w;
    }
    __syncthreads();
    const int oc = tid >> 2;          // output row offset (= input col)
    const int rb = (tid & 3) * 16;    // output col chunk (= input rows)
    u16x8 o0, o1;
#pragma unroll
    for (int j = 0; j < 8; ++j) {
      BU a, bz;
      a.b = __float2bfloat16(tile[rb + j][oc]);
      bz.b = __float2bfloat16(tile[rb + 8 + j][oc]);
      o0[j] = a.u;
      o1[j] = bz.u;
    }
    __hip_bfloat16* d = &dst[(size_t)(c0 + oc) * ldout + r0 + rb];
    *(u16x8*)d = o0;
    *(u16x8*)(d + 8) = o1;
  }
}

// ---------------------------------------------------------------------------
// Fused GEMM dispatch: blocks [0,512) = value projection (per-batch
// M=4096,N=512,K=512, C scattered bf16 to vflat[(b*8+h)*4096*64 + s*64 + dh]);
// blocks [512,704) = offset+logit projection (M=8192,N=384,K=1536 split-bf16,
// A wraps k>=1024 back to hi block; C fp32 +bias to projbuf ldc=384).
// 128x128 tile, BK=64, global_load_lds(16B) staging, 4 waves (2x2).
// ---------------------------------------------------------------------------
__global__ __launch_bounds__(256) void fused_gemm(
    const __hip_bfloat16* __restrict__ qsplit,
    const __hip_bfloat16* __restrict__ Wcat,
    const float* __restrict__ bias_cat, float* __restrict__ projbuf,
    const __hip_bfloat16* __restrict__ fmapT,
    const __hip_bfloat16* __restrict__ WvT, __hip_bfloat16* __restrict__ vflat) {
  __shared__ unsigned short As[128 * 64];
  __shared__ unsigned short Bs[128 * 64];
  const int blk = blockIdx.x;
  const int tid = threadIdx.x;
  const int lane = tid & 63;
  const int wave = tid >> 6;
  const int wm = (wave & 1) * 64, wn = (wave >> 1) * 64;
  const int l15 = lane & 15, quad = lane >> 4;

  const __hip_bfloat16 *A, *Bm;
  __hip_bfloat16* vout = nullptr;
  int lda, ldb, Kt, m0, n0, mode;
  bool awrap;
  if (blk < 512) {
    const int b = blk >> 7, r = blk & 127;
    m0 = (r >> 2) * 128;
    n0 = (r & 3) * 128;
    A = fmapT + (size_t)b * 4096 * 512; lda = 512;
    Bm = WvT; ldb = 512; Kt = 512;
    mode = 1; awrap = false;
    vout = vflat + (size_t)b * 8 * 4096 * 64;
  } else {
    const int pid = blk - 512;
    m0 = (pid & 63) * 128;
    n0 = (pid >> 6) * 128;
    A = qsplit; lda = 1024;
    Bm = Wcat; ldb = 1536; Kt = 1536;
    mode = 0; awrap = true;
  }

  f32x4 acc[4][4] = {};
  const int srow = lane >> 3;        // 0..7
  const int scol = (lane & 7) * 8;   // element offset 0..56

  for (int k0 = 0; k0 < Kt; k0 += 64) {
    const int ka = (awrap && k0 >= 1024) ? k0 - 1024 : k0;
#pragma unroll
    for (int i = 0; i < 4; ++i) {
      const int j = wave * 4 + i;        // chunk 0..15
      const int r = j * 8 + srow;        // row 0..127
      GLOAD_LDS16(A + (size_t)(m0 + r) * lda + ka + scol, As + j * 512);
      GLOAD_LDS16(Bm + (size_t)(n0 + r) * ldb + k0 + scol, Bs + j * 512);
    }
    __syncthreads();
#pragma unroll
    for (int ks = 0; ks < 2; ++ks) {
      bf16x8 af[4], bfr[4];
#pragma unroll
      for (int i = 0; i < 4; ++i)
        af[i] = *(const bf16x8*)&As[(wm + i * 16 + l15) * 64 + ks * 32 + quad * 8];
#pragma unroll
      for (int j = 0; j < 4; ++j)
        bfr[j] = *(const bf16x8*)&Bs[(wn + j * 16 + l15) * 64 + ks * 32 + quad * 8];
#pragma unroll
      for (int i = 0; i < 4; ++i)
#pragma unroll
        for (int j = 0; j < 4; ++j)
          acc[i][j] = __builtin_amdgcn_mfma_f32_16x16x32_bf16(af[i], bfr[j], acc[i][j], 0, 0, 0);
    }
    __syncthreads();
  }

  if (mode == 0) {
#pragma unroll
    for (int i = 0; i < 4; ++i) {
      const int mbase = m0 + wm + i * 16 + quad * 4;
#pragma unroll
      for (int j = 0; j < 4; ++j) {
        const int n = n0 + wn + j * 16 + l15;
        const float bb = bias_cat[n];
#pragma unroll
        for (int r = 0; r < 4; ++r)
          projbuf[(size_t)(mbase + r) * 384 + n] = acc[i][j][r] + bb;
      }
    }
  } else {
#pragma unroll
    for (int i = 0; i < 4; ++i) {
      const int mbase = m0 + wm + i * 16 + quad * 4;  // spatial index s
#pragma unroll
      for (int j = 0; j < 4; ++j) {
        const int ng = n0 + wn + j * 16 + l15;
        const int head = ng >> 6, dh = ng & 63;
#pragma unroll
        for (int r = 0; r < 4; ++r)
          vout[(size_t)head * (4096 * 64) + (size_t)(mbase + r) * 64 + dh] =
              __float2bfloat16(acc[i][j][r]);
      }
    }
  }
}

// ---------------------------------------------------------------------------
// Fused softmax + position math + bilinear gather.
// Block = (b,t) via XCD swizzle. Wave 0 first computes the block's 8 heads x
// 16 points of weights into LDS (lane = h*8 + point-pair; per-block redundancy
// only). Then 4 waves x 2 heads each: lanes 0..31 points 0..7, lanes 32..63
// points 8..15, lane covers dh pair (2k,2k+1) via uint loads of bf16 vflat;
// halves combined with shfl_xor(32).
// ---------------------------------------------------------------------------
__global__ __launch_bounds__(256) void sample_kernel(
    const float* __restrict__ ref_xy, const float* __restrict__ projbuf,
    const unsigned int* __restrict__ vflat2, unsigned int* __restrict__ ctx2) {
  __shared__ float4 wsm[8][16];  // {wx0, wx1, wy0*aw, wy1*aw}
  __shared__ int bsm[8][16];     // base dword index (yA*64+xA)*32
  const int blk = blockIdx.x;
  const int bt = (blk & 7) * 1024 + (blk >> 3);  // XCD-contiguous bt ranges
  const int b = bt >> 11;                        // T = 2048
  const int tid = threadIdx.x;
  const int wave = tid >> 6;
  const int lane = tid & 63;
  const int l31 = lane & 31;
  const bool hiHalf = lane >= 32;

  if (tid < 64) {
    const int h = tid >> 3, pi = tid & 7;
    const float ref_x = ref_xy[bt * 2 + 0];
    const float ref_y = ref_xy[bt * 2 + 1];
    const float* prow = projbuf + (size_t)bt * 384;
    const float* lg = prow + 256 + h * 16;
    float lv[16];
    float mx = -1e30f;
#pragma unroll
    for (int p = 0; p < 16; ++p) {
      lv[p] = lg[p];
      mx = fmaxf(mx, lv[p]);
    }
    float sum = 0.f;
#pragma unroll
    for (int p = 0; p < 16; ++p) {
      lv[p] = __expf(lv[p] - mx);
      sum += lv[p];
    }
    const float inv = 1.0f / sum;
    const float* of = prow + h * 32;
#pragma unroll
    for (int pq = 0; pq < 2; ++pq) {
      const int p = pi + pq * 8;
      const float aw = inv * lv[p];
      const float2 o2 = *(const float2*)&of[p * 2];
      const float ix = (ref_x + RADIUS * o2.x) * (float)(WFi - 1);
      const float iy = (ref_y + RADIUS * o2.y) * (float)(HFi - 1);
      const float ix0f = floorf(ix), iy0f = floorf(iy);
      const float fx = ix - ix0f, fy = iy - iy0f;
      const int ix0 = (int)ix0f, iy0 = (int)iy0f;

      float wx0 = 1.f - fx, wx1 = fx;
      float wy0 = 1.f - fy, wy1 = fy;
      if (ix0 == -1) { wx0 = fx; wx1 = 0.f; }
      if (ix0 == 63) { wx0 = 0.f; wx1 = 1.f - fx; }
      if (ix0 < -1 || ix0 > 63) { wx0 = 0.f; wx1 = 0.f; }
      if (iy0 == -1) { wy0 = fy; wy1 = 0.f; }
      if (iy0 == 63) { wy0 = 0.f; wy1 = 1.f - fy; }
      if (iy0 < -1 || iy0 > 63) { wy0 = 0.f; wy1 = 0.f; }
      const int xA = min(max(ix0, 0), WFi - 2);
      const int yA = min(max(iy0, 0), HFi - 2);

      wsm[h][p] = make_float4(wx0, wx1, wy0 * aw, wy1 * aw);
      bsm[h][p] = (yA * WFi + xA) * 32;
    }
  }
  __syncthreads();

  for (int h = wave; h < Hh; h += 4) {
    const float4* wq = &wsm[h][hiHalf ? 8 : 0];
    const int* bq = &bsm[h][hiHalf ? 8 : 0];
    const unsigned int* vb = vflat2 + (size_t)(b * 8 + h) * (4096 * 32) + l31;

    float acc0 = 0.f, acc1 = 0.f;
#pragma unroll
    for (int pp = 0; pp < 8; ++pp) {
      const float4 w4 = wq[pp];
      const unsigned int* r0 = vb + bq[pp];

      const unsigned int v00 = r0[0], v10 = r0[32];
      const unsigned int v01 = r0[2048], v11 = r0[2080];

      const float w00 = w4.x * w4.z, w10 = w4.y * w4.z;
      const float w01 = w4.x * w4.w, w11 = w4.y * w4.w;

      const float e00 = __uint_as_float(v00 << 16), o00 = __uint_as_float(v00 & 0xffff0000u);
      const float e10 = __uint_as_float(v10 << 16), o10 = __uint_as_float(v10 & 0xffff0000u);
      const float e01 = __uint_as_float(v01 << 16), o01 = __uint_as_float(v01 & 0xffff0000u);
      const float e11 = __uint_as_float(v11 << 16), o11 = __uint_as_float(v11 & 0xffff0000u);

      acc0 = fmaf(w00, e00, acc0);
      acc1 = fmaf(w00, o00, acc1);
      acc0 = fmaf(w10, e10, acc0);
      acc1 = fmaf(w10, o10, acc1);
      acc0 = fmaf(w01, e01, acc0);
      acc1 = fmaf(w01, o01, acc1);
      acc0 = fmaf(w11, e11, acc0);
      acc1 = fmaf(w11, o11, acc1);
    }

    acc0 += __shfl_xor(acc0, 32, 64);
    acc1 += __shfl_xor(acc1, 32, 64);
    if (!hiHalf) {
      union { __hip_bfloat16 b; unsigned short u; } c0, c1;
      c0.b = __float2bfloat16(acc0);
      c1.b = __float2bfloat16(acc1);
      ctx2[(size_t)bt * 256 + h * 32 + l31] = ((unsigned int)c1.u << 16) | c0.u;
    }
  }
}

// ---------------------------------------------------------------------------
// Output projection: C[m][n] = sum_k ctx[m*512+k] * WoutT[n*512+k] + b_out[n]
// 128x128 tile, BK=64, global_load_lds(16B) staging. grid (64, 4).
// ---------------------------------------------------------------------------
__global__ __launch_bounds__(256) void outproj_kernel(
    const __hip_bfloat16* __restrict__ A, const __hip_bfloat16* __restrict__ Bm,
    const float* __restrict__ bias, float* __restrict__ C) {
  __shared__ unsigned short As[128 * 64];
  __shared__ unsigned short Bs[128 * 64];
  const int tid = threadIdx.x;
  const int lane = tid & 63;
  const int wave = tid >> 6;
  const int wm = (wave & 1) * 64, wn = (wave >> 1) * 64;
  const int l15 = lane & 15, quad = lane >> 4;
  const int m0 = blockIdx.x * 128, n0 = blockIdx.y * 128;

  f32x4 acc[4][4] = {};
  const int srow = lane >> 3;
  const int scol = (lane & 7) * 8;

  for (int k0 = 0; k0 < 512; k0 += 64) {
#pragma unroll
    for (int i = 0; i < 4; ++i) {
      const int j = wave * 4 + i;
      const int r = j * 8 + srow;
      GLOAD_LDS16(A + (size_t)(m0 + r) * 512 + k0 + scol, As + j * 512);
      GLOAD_LDS16(Bm + (size_t)(n0 + r) * 512 + k0 + scol, Bs + j * 512);
    }
    __syncthreads();
#pragma unroll
    for (int ks = 0; ks < 2; ++ks) {
      bf16x8 af[4], bfr[4];
#pragma unroll
      for (int i = 0; i < 4; ++i)
        af[i] = *(const bf16x8*)&As[(wm + i * 16 + l15) * 64 + ks * 32 + quad * 8];
#pragma unroll
      for (int j = 0; j < 4; ++j)
        bfr[j] = *(const bf16x8*)&Bs[(wn + j * 16 + l15) * 64 + ks * 32 + quad * 8];
#pragma unroll
      for (int i = 0; i < 4; ++i)
#pragma unroll
        for (int j = 0; j < 4; ++j)
          acc[i][j] = __builtin_amdgcn_mfma_f32_16x16x32_bf16(af[i], bfr[j], acc[i][j], 0, 0, 0);
    }
    __syncthreads();
  }

#pragma unroll
  for (int i = 0; i < 4; ++i) {
    const int mbase = m0 + wm + i * 16 + quad * 4;
#pragma unroll
    for (int j = 0; j < 4; ++j) {
      const int n = n0 + wn + j * 16 + l15;
      const float bb = bias[n];
#pragma unroll
      for (int r = 0; r < 4; ++r)
        C[(size_t)(mbase + r) * 512 + n] = acc[i][j][r] + bb;
    }
  }
}

// ---------------------------------------------------------------------------
extern "C" void kernel_launch(void* const* d_in, const int* in_sizes, int n_in,
                              void* d_out, int out_size, void* d_ws, size_t ws_size,
                              hipStream_t stream) {
  const float* q      = (const float*)d_in[0];
  const float* fmap   = (const float*)d_in[1];
  const float* ref_xy = (const float*)d_in[2];
  const float* Wv     = (const float*)d_in[3];
  const float* W_off  = (const float*)d_in[4];
  const float* b_off  = (const float*)d_in[5];
  const float* W_w    = (const float*)d_in[6];
  const float* b_w    = (const float*)d_in[7];
  const float* W_out  = (const float*)d_in[8];
  const float* b_out  = (const float*)d_in[9];
  float* out = (float*)d_out;

  // workspace (no aliasing; ~71 MB total)
  char* ws = (char*)d_ws;
  __hip_bfloat16* qsplit = (__hip_bfloat16*)ws; ws += (size_t)8192 * 1024 * 2;
  __hip_bfloat16* Wcat   = (__hip_bfloat16*)ws; ws += (size_t)384 * 1536 * 2;
  float* bias_cat        = (float*)ws;          ws += 384 * 4;
  float* projbuf         = (float*)ws;          ws += (size_t)8192 * 384 * 4;
  __hip_bfloat16* fmapT  = (__hip_bfloat16*)ws; ws += (size_t)4 * 4096 * 512 * 2;
  __hip_bfloat16* WvT    = (__hip_bfloat16*)ws; ws += (size_t)512 * 512 * 2;
  __hip_bfloat16* WoutT  = (__hip_bfloat16*)ws; ws += (size_t)512 * 512 * 2;
  __hip_bfloat16* vflat  = (__hip_bfloat16*)ws; ws += (size_t)4 * 8 * 4096 * 64 * 2;
  __hip_bfloat16* ctxb   = (__hip_bfloat16*)ws; ws += (size_t)8192 * 512 * 2;

  // 1) fused prep: q split, Wcat/bias, weight + fmap transposes
  prep_kernel<<<dim3(8576), 256, 0, stream>>>(
      q, qsplit, W_off, W_w, b_off, b_w, Wcat, bias_cat, Wv, WvT, W_out, WoutT,
      fmap, fmapT);

  // 2) fused GEMMs: value projection (512 blocks) + offset/logit projection
  //    (192 blocks) in one dispatch
  fused_gemm<<<dim3(704), 256, 0, stream>>>(
      qsplit, Wcat, bias_cat, projbuf, fmapT, WvT, vflat);

  // 3) fused softmax + position math + bilinear gather -> ctx bf16
  sample_kernel<<<dim3(Bsz * T), 256, 0, stream>>>(
      ref_xy, projbuf, (const unsigned int*)vflat, (unsigned int*)ctxb);

  // 4) output projection + bias -> fp32 out
  outproj_kernel<<<dim3(64, 4), 256, 0, stream>>>(ctxb, WoutT, b_out, out);
}

// Round 7
// 195.081 us; speedup vs baseline: 2.3239x; 1.0272x over previous
//
#include <hip/hip_runtime.h>
#include <hip/hip_bf16.h>
#include <math.h>

// Problem constants
constexpr int Bsz = 4, T = 2048, Hh = 8;
constexpr int HFi = 64, WFi = 64;
constexpr float RADIUS = 0.08f;

typedef __bf16 bf16x8 __attribute__((ext_vector_type(8)));
typedef float f32x4 __attribute__((ext_vector_type(4)));
typedef unsigned short u16x8 __attribute__((ext_vector_type(8)));

typedef const __attribute__((address_space(1))) void* gcptr;
typedef __attribute__((address_space(3))) void* lptr;

#define GLOAD_LDS16(g, l) \
  __builtin_amdgcn_global_load_lds((gcptr)(const void*)(g), (lptr)(void*)(l), 16, 0, 0)

union BU { __hip_bfloat16 b; unsigned short u; };

// ---------------------------------------------------------------------------
// Combined prep kernel (one dispatch for all input conditioning):
//  blocks [0,4096):     split q into hi/lo bf16 (qsplit[m][0:512]=hi,[512:1024]=lo)
//  blocks [4096,6400):  build Wcat (384x1536 B^T = [W_hi|W_hi|W_lo]) + bias_cat
//  blocks [6400,6528):  transpose Wv -> WvT, W_out -> WoutT (64x64 tiles)
//  blocks [6528,8576):  transpose fmap (B,512,4096) -> fmapT (B,4096,512) bf16
// ---------------------------------------------------------------------------
__global__ __launch_bounds__(256) void prep_kernel(
    const float* __restrict__ q, __hip_bfloat16* __restrict__ qsplit,
    const float* __restrict__ W_off, const float* __restrict__ W_w,
    const float* __restrict__ b_off, const float* __restrict__ b_w,
    __hip_bfloat16* __restrict__ Wcat, float* __restrict__ bias_cat,
    const float* __restrict__ Wv, __hip_bfloat16* __restrict__ WvT,
    const float* __restrict__ W_out, __hip_bfloat16* __restrict__ WoutT,
    const float* __restrict__ fmap, __hip_bfloat16* __restrict__ fmapT) {
  __shared__ float tile[64][65];
  const int blk = blockIdx.x;
  const int tid = threadIdx.x;
  if (blk < 4096) {
    const int idx = blk * 256 + tid;  // 8192*128
    const int m = idx >> 7, kq = (idx & 127) * 4;
    float4 v = *(const float4*)&q[(size_t)m * 512 + kq];
    union { __hip_bfloat16 b[4]; ushort4 u; } hi, lo;
    float f[4] = {v.x, v.y, v.z, v.w};
#pragma unroll
    for (int i = 0; i < 4; ++i) {
      hi.b[i] = __float2bfloat16(f[i]);
      lo.b[i] = __float2bfloat16(f[i] - __bfloat162float(hi.b[i]));
    }
    *(ushort4*)&qsplit[(size_t)m * 1024 + kq] = hi.u;
    *(ushort4*)&qsplit[(size_t)m * 1024 + 512 + kq] = lo.u;
    return;
  }
  if (blk < 6400) {
    const int idx = (blk - 4096) * 256 + tid;  // 384*1536 = 589824
    const int n = idx / 1536, kp = idx % 1536;
    const int k = kp & 511;
    const float w = (n < 256) ? W_off[(size_t)k * 256 + n]
                              : W_w[(size_t)k * 128 + (n - 256)];
    const __hip_bfloat16 h = __float2bfloat16(w);
    const __hip_bfloat16 o =
        (kp < 1024) ? h : __float2bfloat16(w - __bfloat162float(h));
    Wcat[(size_t)n * 1536 + kp] = o;
    if (idx < 384) bias_cat[idx] = (idx < 256) ? b_off[idx] : b_w[idx - 256];
    return;
  }
  // --- 64x64 transpose segments ---
  const float* src;
  __hip_bfloat16* dst;
  int ldin, ldout, r0, c0;
  if (blk < 6528) {
    const int t2 = blk - 6400;  // 0..127
    src = (t2 < 64) ? Wv : W_out;
    dst = (t2 < 64) ? WvT : WoutT;
    ldin = 512; ldout = 512;
    const int tl = t2 & 63;
    r0 = (tl >> 3) * 64; c0 = (tl & 7) * 64;
  } else {
    const int t3 = blk - 6528;          // 0..2047
    const int b = t3 >> 9;              // 512 tiles per batch
    const int tl = t3 & 511;
    r0 = (tl >> 6) * 64;                // channel rows
    c0 = (tl & 63) * 64;                // spatial cols
    src = fmap + (size_t)b * 512 * 4096;
    dst = fmapT + (size_t)b * 4096 * 512;
    ldin = 4096; ldout = 512;
  }
  {
    const int tr = tid >> 2;          // 0..63 input row
    const int tc = (tid & 3) * 16;    // input col chunk
    const float* s = &src[(size_t)(r0 + tr) * ldin + c0 + tc];
#pragma unroll
    for (int j4 = 0; j4 < 4; ++j4) {
      float4 v = *(const float4*)&s[j4 * 4];
      tile[tr][tc + j4 * 4 + 0] = v.x;
      tile[tr][tc + j4 * 4 + 1] = v.y;
      tile[tr][tc + j4 * 4 + 2] = v.z;
      tile[tr][tc + j4 * 4 + 3] = v.w;
    }
    __syncthreads();
    const int oc = tid >> 2;          // output row offset (= input col)
    const int rb = (tid & 3) * 16;    // output col chunk (= input rows)
    u16x8 o0, o1;
#pragma unroll
    for (int j = 0; j < 8; ++j) {
      BU a, bz;
      a.b = __float2bfloat16(tile[rb + j][oc]);
      bz.b = __float2bfloat16(tile[rb + 8 + j][oc]);
      o0[j] = a.u;
      o1[j] = bz.u;
    }
    __hip_bfloat16* d = &dst[(size_t)(c0 + oc) * ldout + r0 + rb];
    *(u16x8*)d = o0;
    *(u16x8*)(d + 8) = o1;
  }
}

// ---------------------------------------------------------------------------
// Fused GEMM dispatch.
//  blocks [0,384):   offset/logit projection, 128x64 tile, K=1536 split-bf16
//                    (A wraps k>=1024 to hi block). Dispatched FIRST: these
//                    are the longest blocks (1.5x vproj) -> no long tail.
//  blocks [384,896): value projection, 128x128 tile, per-batch M=4096 N=512
//                    K=512; C retiled through LDS -> coalesced bf16 stores to
//                    vflat[(b*8+h)*4096*64 + s*64 + dh].
// LDS XOR swizzle: staged row r holds global cols (c ^ ((r&1)*32)); fragment
// reads XOR the same term -> conflict-free ds_read_b128 (8 dwords/bank).
// ---------------------------------------------------------------------------
__global__ __launch_bounds__(256) void fused_gemm(
    const __hip_bfloat16* __restrict__ qsplit,
    const __hip_bfloat16* __restrict__ Wcat,
    const float* __restrict__ bias_cat, float* __restrict__ projbuf,
    const __hip_bfloat16* __restrict__ fmapT,
    const __hip_bfloat16* __restrict__ WvT, __hip_bfloat16* __restrict__ vflat) {
  __shared__ unsigned short lds[2 * 128 * 64];  // As | Bs ; reused as C-tile
  unsigned short* As = lds;
  unsigned short* Bs = lds + 128 * 64;
  const int blk = blockIdx.x;
  const int tid = threadIdx.x;
  const int lane = tid & 63;
  const int wave = tid >> 6;
  const int l15 = lane & 15, quad = lane >> 4;
  const int srow = lane >> 3;                       // 0..7
  const int scol = ((lane & 7) * 8) ^ ((srow & 1) * 32);  // swizzled src col
  const int fxor = (l15 & 1) * 32;                  // fragment-read XOR

  if (blk < 384) {
    // ---- projection GEMM: 128x64, K=1536 ----
    const int m0 = (blk & 63) * 128;
    const int n0 = (blk >> 6) * 64;
    const int wm = (wave & 1) * 64, wn = (wave >> 1) * 32;
    f32x4 acc[4][2] = {};
    for (int k0 = 0; k0 < 1536; k0 += 64) {
      const int ka = (k0 >= 1024) ? k0 - 1024 : k0;
#pragma unroll
      for (int i = 0; i < 4; ++i) {
        const int j = wave * 4 + i;
        const int r = j * 8 + srow;
        GLOAD_LDS16(qsplit + (size_t)(m0 + r) * 1024 + ka + scol, As + j * 512);
      }
#pragma unroll
      for (int i = 0; i < 2; ++i) {
        const int j = wave * 2 + i;
        const int r = j * 8 + srow;
        GLOAD_LDS16(Wcat + (size_t)(n0 + r) * 1536 + k0 + scol, Bs + j * 512);
      }
      __syncthreads();
#pragma unroll
      for (int ks = 0; ks < 2; ++ks) {
        bf16x8 af[4], bfr[2];
#pragma unroll
        for (int i = 0; i < 4; ++i)
          af[i] = *(const bf16x8*)&As[(wm + i * 16 + l15) * 64 + ((ks * 32 + quad * 8) ^ fxor)];
#pragma unroll
        for (int j = 0; j < 2; ++j)
          bfr[j] = *(const bf16x8*)&Bs[(wn + j * 16 + l15) * 64 + ((ks * 32 + quad * 8) ^ fxor)];
#pragma unroll
        for (int i = 0; i < 4; ++i)
#pragma unroll
          for (int j = 0; j < 2; ++j)
            acc[i][j] = __builtin_amdgcn_mfma_f32_16x16x32_bf16(af[i], bfr[j], acc[i][j], 0, 0, 0);
      }
      __syncthreads();
    }
#pragma unroll
    for (int i = 0; i < 4; ++i) {
      const int mbase = m0 + wm + i * 16 + quad * 4;
#pragma unroll
      for (int j = 0; j < 2; ++j) {
        const int n = n0 + wn + j * 16 + l15;
        const float bb = bias_cat[n];
#pragma unroll
        for (int r = 0; r < 4; ++r)
          projbuf[(size_t)(mbase + r) * 384 + n] = acc[i][j][r] + bb;
      }
    }
  } else {
    // ---- value projection GEMM: 128x128, K=512 ----
    const int vb = blk - 384;
    const int b = vb >> 7, rr = vb & 127;
    const int m0 = (rr >> 2) * 128;
    const int n0 = (rr & 3) * 128;
    const __hip_bfloat16* A = fmapT + (size_t)b * 4096 * 512;
    __hip_bfloat16* vout = vflat + (size_t)b * 8 * 4096 * 64;
    const int wm = (wave & 1) * 64, wn = (wave >> 1) * 64;
    f32x4 acc[4][4] = {};
    for (int k0 = 0; k0 < 512; k0 += 64) {
#pragma unroll
      for (int i = 0; i < 4; ++i) {
        const int j = wave * 4 + i;
        const int r = j * 8 + srow;
        GLOAD_LDS16(A + (size_t)(m0 + r) * 512 + k0 + scol, As + j * 512);
        GLOAD_LDS16(WvT + (size_t)(n0 + r) * 512 + k0 + scol, Bs + j * 512);
      }
      __syncthreads();
#pragma unroll
      for (int ks = 0; ks < 2; ++ks) {
        bf16x8 af[4], bfr[4];
#pragma unroll
        for (int i = 0; i < 4; ++i)
          af[i] = *(const bf16x8*)&As[(wm + i * 16 + l15) * 64 + ((ks * 32 + quad * 8) ^ fxor)];
#pragma unroll
        for (int j = 0; j < 4; ++j)
          bfr[j] = *(const bf16x8*)&Bs[(wn + j * 16 + l15) * 64 + ((ks * 32 + quad * 8) ^ fxor)];
#pragma unroll
        for (int i = 0; i < 4; ++i)
#pragma unroll
          for (int j = 0; j < 4; ++j)
            acc[i][j] = __builtin_amdgcn_mfma_f32_16x16x32_bf16(af[i], bfr[j], acc[i][j], 0, 0, 0);
      }
      __syncthreads();
    }
    // epilogue: retile C through LDS (32 KB, As/Bs dead) -> coalesced stores
    unsigned short* Ct = lds;  // [128][128] bf16
#pragma unroll
    for (int i = 0; i < 4; ++i) {
#pragma unroll
      for (int j = 0; j < 4; ++j) {
        const int ngl = wn + j * 16 + l15;
#pragma unroll
        for (int r = 0; r < 4; ++r) {
          const int sl = wm + i * 16 + quad * 4 + r;
          BU u;
          u.b = __float2bfloat16(acc[i][j][r]);
          Ct[sl * 128 + ngl] = u.u;
        }
      }
    }
    __syncthreads();
#pragma unroll
    for (int c = 0; c < 8; ++c) {
      const int sl = (tid >> 4) + c * 16;
      const int chunk = tid & 15;
      const int head = (n0 >> 6) + (chunk >> 3);
      const int dh = (chunk & 7) * 8;
      *(u16x8*)(vout + (size_t)head * (4096 * 64) + (size_t)(m0 + sl) * 64 + dh) =
          *(const u16x8*)&Ct[sl * 128 + chunk * 8];
    }
  }
}

// ---------------------------------------------------------------------------
// Fused softmax + position math + bilinear gather.
// Block = (b,t) via XCD swizzle. Wave 0 computes the block's 8 heads x 16
// points of weights into LDS. Then 4 waves x 2 heads: lanes 0..31 points 0..7,
// lanes 32..63 points 8..15, lane covers dh pair (2k,2k+1) via uint loads of
// bf16 vflat; halves combined with shfl_xor(32).
// ---------------------------------------------------------------------------
__global__ __launch_bounds__(256) void sample_kernel(
    const float* __restrict__ ref_xy, const float* __restrict__ projbuf,
    const unsigned int* __restrict__ vflat2, unsigned int* __restrict__ ctx2) {
  __shared__ float4 wsm[8][16];  // {wx0, wx1, wy0*aw, wy1*aw}
  __shared__ int bsm[8][16];     // base dword index (yA*64+xA)*32
  const int blk = blockIdx.x;
  const int bt = (blk & 7) * 1024 + (blk >> 3);  // XCD-contiguous bt ranges
  const int b = bt >> 11;                        // T = 2048
  const int tid = threadIdx.x;
  const int wave = tid >> 6;
  const int lane = tid & 63;
  const int l31 = lane & 31;
  const bool hiHalf = lane >= 32;

  if (tid < 64) {
    const int h = tid >> 3, pi = tid & 7;
    const float ref_x = ref_xy[bt * 2 + 0];
    const float ref_y = ref_xy[bt * 2 + 1];
    const float* prow = projbuf + (size_t)bt * 384;
    const float* lg = prow + 256 + h * 16;
    float lv[16];
    float mx = -1e30f;
#pragma unroll
    for (int p = 0; p < 16; ++p) {
      lv[p] = lg[p];
      mx = fmaxf(mx, lv[p]);
    }
    float sum = 0.f;
#pragma unroll
    for (int p = 0; p < 16; ++p) {
      lv[p] = __expf(lv[p] - mx);
      sum += lv[p];
    }
    const float inv = 1.0f / sum;
    const float* of = prow + h * 32;
#pragma unroll
    for (int pq = 0; pq < 2; ++pq) {
      const int p = pi + pq * 8;
      const float aw = inv * lv[p];
      const float2 o2 = *(const float2*)&of[p * 2];
      const float ix = (ref_x + RADIUS * o2.x) * (float)(WFi - 1);
      const float iy = (ref_y + RADIUS * o2.y) * (float)(HFi - 1);
      const float ix0f = floorf(ix), iy0f = floorf(iy);
      const float fx = ix - ix0f, fy = iy - iy0f;
      const int ix0 = (int)ix0f, iy0 = (int)iy0f;

      float wx0 = 1.f - fx, wx1 = fx;
      float wy0 = 1.f - fy, wy1 = fy;
      if (ix0 == -1) { wx0 = fx; wx1 = 0.f; }
      if (ix0 == 63) { wx0 = 0.f; wx1 = 1.f - fx; }
      if (ix0 < -1 || ix0 > 63) { wx0 = 0.f; wx1 = 0.f; }
      if (iy0 == -1) { wy0 = fy; wy1 = 0.f; }
      if (iy0 == 63) { wy0 = 0.f; wy1 = 1.f - fy; }
      if (iy0 < -1 || iy0 > 63) { wy0 = 0.f; wy1 = 0.f; }
      const int xA = min(max(ix0, 0), WFi - 2);
      const int yA = min(max(iy0, 0), HFi - 2);

      wsm[h][p] = make_float4(wx0, wx1, wy0 * aw, wy1 * aw);
      bsm[h][p] = (yA * WFi + xA) * 32;
    }
  }
  __syncthreads();

  for (int h = wave; h < Hh; h += 4) {
    const float4* wq = &wsm[h][hiHalf ? 8 : 0];
    const int* bq = &bsm[h][hiHalf ? 8 : 0];
    const unsigned int* vb = vflat2 + (size_t)(b * 8 + h) * (4096 * 32) + l31;

    float acc0 = 0.f, acc1 = 0.f;
#pragma unroll
    for (int pp = 0; pp < 8; ++pp) {
      const float4 w4 = wq[pp];
      const unsigned int* r0 = vb + bq[pp];

      const unsigned int v00 = r0[0], v10 = r0[32];
      const unsigned int v01 = r0[2048], v11 = r0[2080];

      const float w00 = w4.x * w4.z, w10 = w4.y * w4.z;
      const float w01 = w4.x * w4.w, w11 = w4.y * w4.w;

      const float e00 = __uint_as_float(v00 << 16), o00 = __uint_as_float(v00 & 0xffff0000u);
      const float e10 = __uint_as_float(v10 << 16), o10 = __uint_as_float(v10 & 0xffff0000u);
      const float e01 = __uint_as_float(v01 << 16), o01 = __uint_as_float(v01 & 0xffff0000u);
      const float e11 = __uint_as_float(v11 << 16), o11 = __uint_as_float(v11 & 0xffff0000u);

      acc0 = fmaf(w00, e00, acc0);
      acc1 = fmaf(w00, o00, acc1);
      acc0 = fmaf(w10, e10, acc0);
      acc1 = fmaf(w10, o10, acc1);
      acc0 = fmaf(w01, e01, acc0);
      acc1 = fmaf(w01, o01, acc1);
      acc0 = fmaf(w11, e11, acc0);
      acc1 = fmaf(w11, o11, acc1);
    }

    acc0 += __shfl_xor(acc0, 32, 64);
    acc1 += __shfl_xor(acc1, 32, 64);
    if (!hiHalf) {
      union { __hip_bfloat16 b; unsigned short u; } c0, c1;
      c0.b = __float2bfloat16(acc0);
      c1.b = __float2bfloat16(acc1);
      ctx2[(size_t)bt * 256 + h * 32 + l31] = ((unsigned int)c1.u << 16) | c0.u;
    }
  }
}

// ---------------------------------------------------------------------------
// Output projection: C[m][n] = sum_k ctx[m*512+k] * WoutT[n*512+k] + b_out[n]
// 128x128 tile, BK=64, global_load_lds(16B) staging, XOR-swizzled LDS.
// ---------------------------------------------------------------------------
__global__ __launch_bounds__(256) void outproj_kernel(
    const __hip_bfloat16* __restrict__ A, const __hip_bfloat16* __restrict__ Bm,
    const float* __restrict__ bias, float* __restrict__ C) {
  __shared__ unsigned short As[128 * 64];
  __shared__ unsigned short Bs[128 * 64];
  const int tid = threadIdx.x;
  const int lane = tid & 63;
  const int wave = tid >> 6;
  const int wm = (wave & 1) * 64, wn = (wave >> 1) * 64;
  const int l15 = lane & 15, quad = lane >> 4;
  const int m0 = blockIdx.x * 128, n0 = blockIdx.y * 128;
  const int srow = lane >> 3;
  const int scol = ((lane & 7) * 8) ^ ((srow & 1) * 32);
  const int fxor = (l15 & 1) * 32;

  f32x4 acc[4][4] = {};

  for (int k0 = 0; k0 < 512; k0 += 64) {
#pragma unroll
    for (int i = 0; i < 4; ++i) {
      const int j = wave * 4 + i;
      const int r = j * 8 + srow;
      GLOAD_LDS16(A + (size_t)(m0 + r) * 512 + k0 + scol, As + j * 512);
      GLOAD_LDS16(Bm + (size_t)(n0 + r) * 512 + k0 + scol, Bs + j * 512);
    }
    __syncthreads();
#pragma unroll
    for (int ks = 0; ks < 2; ++ks) {
      bf16x8 af[4], bfr[4];
#pragma unroll
      for (int i = 0; i < 4; ++i)
        af[i] = *(const bf16x8*)&As[(wm + i * 16 + l15) * 64 + ((ks * 32 + quad * 8) ^ fxor)];
#pragma unroll
      for (int j = 0; j < 4; ++j)
        bfr[j] = *(const bf16x8*)&Bs[(wn + j * 16 + l15) * 64 + ((ks * 32 + quad * 8) ^ fxor)];
#pragma unroll
      for (int i = 0; i < 4; ++i)
#pragma unroll
        for (int j = 0; j < 4; ++j)
          acc[i][j] = __builtin_amdgcn_mfma_f32_16x16x32_bf16(af[i], bfr[j], acc[i][j], 0, 0, 0);
    }
    __syncthreads();
  }

#pragma unroll
  for (int i = 0; i < 4; ++i) {
    const int mbase = m0 + wm + i * 16 + quad * 4;
#pragma unroll
    for (int j = 0; j < 4; ++j) {
      const int n = n0 + wn + j * 16 + l15;
      const float bb = bias[n];
#pragma unroll
      for (int r = 0; r < 4; ++r)
        C[(size_t)(mbase + r) * 512 + n] = acc[i][j][r] + bb;
    }
  }
}

// ---------------------------------------------------------------------------
extern "C" void kernel_launch(void* const* d_in, const int* in_sizes, int n_in,
                              void* d_out, int out_size, void* d_ws, size_t ws_size,
                              hipStream_t stream) {
  const float* q      = (const float*)d_in[0];
  const float* fmap   = (const float*)d_in[1];
  const float* ref_xy = (const float*)d_in[2];
  const float* Wv     = (const float*)d_in[3];
  const float* W_off  = (const float*)d_in[4];
  const float* b_off  = (const float*)d_in[5];
  const float* W_w    = (const float*)d_in[6];
  const float* b_w    = (const float*)d_in[7];
  const float* W_out  = (const float*)d_in[8];
  const float* b_out  = (const float*)d_in[9];
  float* out = (float*)d_out;

  // workspace (no aliasing; ~71 MB total)
  char* ws = (char*)d_ws;
  __hip_bfloat16* qsplit = (__hip_bfloat16*)ws; ws += (size_t)8192 * 1024 * 2;
  __hip_bfloat16* Wcat   = (__hip_bfloat16*)ws; ws += (size_t)384 * 1536 * 2;
  float* bias_cat        = (float*)ws;          ws += 384 * 4;
  float* projbuf         = (float*)ws;          ws += (size_t)8192 * 384 * 4;
  __hip_bfloat16* fmapT  = (__hip_bfloat16*)ws; ws += (size_t)4 * 4096 * 512 * 2;
  __hip_bfloat16* WvT    = (__hip_bfloat16*)ws; ws += (size_t)512 * 512 * 2;
  __hip_bfloat16* WoutT  = (__hip_bfloat16*)ws; ws += (size_t)512 * 512 * 2;
  __hip_bfloat16* vflat  = (__hip_bfloat16*)ws; ws += (size_t)4 * 8 * 4096 * 64 * 2;
  __hip_bfloat16* ctxb   = (__hip_bfloat16*)ws; ws += (size_t)8192 * 512 * 2;

  // 1) fused prep: q split, Wcat/bias, weight + fmap transposes
  prep_kernel<<<dim3(8576), 256, 0, stream>>>(
      q, qsplit, W_off, W_w, b_off, b_w, Wcat, bias_cat, Wv, WvT, W_out, WoutT,
      fmap, fmapT);

  // 2) fused GEMMs: proj (384 long blocks FIRST) + value projection (512)
  fused_gemm<<<dim3(896), 256, 0, stream>>>(
      qsplit, Wcat, bias_cat, projbuf, fmapT, WvT, vflat);

  // 3) fused softmax + position math + bilinear gather -> ctx bf16
  sample_kernel<<<dim3(Bsz * T), 256, 0, stream>>>(
      ref_xy, projbuf, (const unsigned int*)vflat, (unsigned int*)ctxb);

  // 4) output projection + bias -> fp32 out
  outproj_kernel<<<dim3(64, 4), 256, 0, stream>>>(ctxb, WoutT, b_out, out);
}

// Round 9
// 187.410 us; speedup vs baseline: 2.4190x; 1.0409x over previous
//
#include <hip/hip_runtime.h>
#include <hip/hip_bf16.h>
#include <math.h>

// Problem constants
constexpr int Bsz = 4, T = 2048, Hh = 8;
constexpr int HFi = 64, WFi = 64;
constexpr float RADIUS = 0.08f;

typedef __bf16 bf16x8 __attribute__((ext_vector_type(8)));
typedef float f32x4 __attribute__((ext_vector_type(4)));
typedef unsigned short u16x8 __attribute__((ext_vector_type(8)));

typedef const __attribute__((address_space(1))) void* gcptr;
typedef __attribute__((address_space(3))) void* lptr;

#define GLOAD_LDS16(g, l) \
  __builtin_amdgcn_global_load_lds((gcptr)(const void*)(g), (lptr)(void*)(l), 16, 0, 0)

union BU { __hip_bfloat16 b; unsigned short u; };

// ---------------------------------------------------------------------------
// Combined prep kernel (one dispatch for all input conditioning):
//  blocks [0,4096):     split q into hi/lo bf16 (qsplit[m][0:512]=hi,[512:1024]=lo)
//  blocks [4096,6400):  build Wcat (384x1536 B^T = [W_hi|W_hi|W_lo]) + bias_cat
//  blocks [6400,6528):  transpose Wv -> WvT, W_out -> WoutT (64x64 tiles)
//  blocks [6528,8576):  transpose fmap (B,512,4096) -> fmapT (B,4096,512) bf16
// ---------------------------------------------------------------------------
__global__ __launch_bounds__(256) void prep_kernel(
    const float* __restrict__ q, __hip_bfloat16* __restrict__ qsplit,
    const float* __restrict__ W_off, const float* __restrict__ W_w,
    const float* __restrict__ b_off, const float* __restrict__ b_w,
    __hip_bfloat16* __restrict__ Wcat, float* __restrict__ bias_cat,
    const float* __restrict__ Wv, __hip_bfloat16* __restrict__ WvT,
    const float* __restrict__ W_out, __hip_bfloat16* __restrict__ WoutT,
    const float* __restrict__ fmap, __hip_bfloat16* __restrict__ fmapT) {
  __shared__ float tile[64][65];
  const int blk = blockIdx.x;
  const int tid = threadIdx.x;
  if (blk < 4096) {
    const int idx = blk * 256 + tid;  // 8192*128
    const int m = idx >> 7, kq = (idx & 127) * 4;
    float4 v = *(const float4*)&q[(size_t)m * 512 + kq];
    union { __hip_bfloat16 b[4]; ushort4 u; } hi, lo;
    float f[4] = {v.x, v.y, v.z, v.w};
#pragma unroll
    for (int i = 0; i < 4; ++i) {
      hi.b[i] = __float2bfloat16(f[i]);
      lo.b[i] = __float2bfloat16(f[i] - __bfloat162float(hi.b[i]));
    }
    *(ushort4*)&qsplit[(size_t)m * 1024 + kq] = hi.u;
    *(ushort4*)&qsplit[(size_t)m * 1024 + 512 + kq] = lo.u;
    return;
  }
  if (blk < 6400) {
    const int idx = (blk - 4096) * 256 + tid;  // 384*1536 = 589824
    const int n = idx / 1536, kp = idx % 1536;
    const int k = kp & 511;
    const float w = (n < 256) ? W_off[(size_t)k * 256 + n]
                              : W_w[(size_t)k * 128 + (n - 256)];
    const __hip_bfloat16 h = __float2bfloat16(w);
    const __hip_bfloat16 o =
        (kp < 1024) ? h : __float2bfloat16(w - __bfloat162float(h));
    Wcat[(size_t)n * 1536 + kp] = o;
    if (idx < 384) bias_cat[idx] = (idx < 256) ? b_off[idx] : b_w[idx - 256];
    return;
  }
  // --- 64x64 transpose segments ---
  const float* src;
  __hip_bfloat16* dst;
  int ldin, ldout, r0, c0;
  if (blk < 6528) {
    const int t2 = blk - 6400;  // 0..127
    src = (t2 < 64) ? Wv : W_out;
    dst = (t2 < 64) ? WvT : WoutT;
    ldin = 512; ldout = 512;
    const int tl = t2 & 63;
    r0 = (tl >> 3) * 64; c0 = (tl & 7) * 64;
  } else {
    const int t3 = blk - 6528;          // 0..2047
    const int b = t3 >> 9;              // 512 tiles per batch
    const int tl = t3 & 511;
    r0 = (tl >> 6) * 64;                // channel rows
    c0 = (tl & 63) * 64;                // spatial cols
    src = fmap + (size_t)b * 512 * 4096;
    dst = fmapT + (size_t)b * 4096 * 512;
    ldin = 4096; ldout = 512;
  }
  {
    const int tr = tid >> 2;          // 0..63 input row
    const int tc = (tid & 3) * 16;    // input col chunk
    const float* s = &src[(size_t)(r0 + tr) * ldin + c0 + tc];
#pragma unroll
    for (int j4 = 0; j4 < 4; ++j4) {
      float4 v = *(const float4*)&s[j4 * 4];
      tile[tr][tc + j4 * 4 + 0] = v.x;
      tile[tr][tc + j4 * 4 + 1] = v.y;
      tile[tr][tc + j4 * 4 + 2] = v.z;
      tile[tr][tc + j4 * 4 + 3] = v.w;
    }
    __syncthreads();
    const int oc = tid >> 2;          // output row offset (= input col)
    const int rb = (tid & 3) * 16;    // output col chunk (= input rows)
    u16x8 o0, o1;
#pragma unroll
    for (int j = 0; j < 8; ++j) {
      BU a, bz;
      a.b = __float2bfloat16(tile[rb + j][oc]);
      bz.b = __float2bfloat16(tile[rb + 8 + j][oc]);
      o0[j] = a.u;
      o1[j] = bz.u;
    }
    __hip_bfloat16* d = &dst[(size_t)(c0 + oc) * ldout + r0 + rb];
    *(u16x8*)d = o0;
    *(u16x8*)(d + 8) = o1;
  }
}

// ---------------------------------------------------------------------------
// Fused GEMM dispatch.
//  blocks [0,384):   offset/logit projection, 128x64 tile, K=1536 split-bf16
//                    (A wraps k>=1024 to hi block). Dispatched FIRST (longest).
//  blocks [384,896): value projection, 128x128 tile, per-batch M=4096 N=512
//                    K=512; C retiled through LDS -> coalesced bf16 stores.
// LDS swizzle: LDS[r][c] holds global[r][c ^ ((r&7)*8)] (elems); staging uses
// scol = ((lane&7)^srow)*8, fragment reads XOR (l15&7)*8. Every ds_read_b128
// then touches all 32 banks at exactly 8 dwords/bank (wave64 floor).
// ---------------------------------------------------------------------------
__global__ __launch_bounds__(256) void fused_gemm(
    const __hip_bfloat16* __restrict__ qsplit,
    const __hip_bfloat16* __restrict__ Wcat,
    const float* __restrict__ bias_cat, float* __restrict__ projbuf,
    const __hip_bfloat16* __restrict__ fmapT,
    const __hip_bfloat16* __restrict__ WvT, __hip_bfloat16* __restrict__ vflat) {
  __shared__ unsigned short lds[2 * 128 * 64];  // As | Bs ; reused as C-tile
  unsigned short* As = lds;
  unsigned short* Bs = lds + 128 * 64;
  const int blk = blockIdx.x;
  const int tid = threadIdx.x;
  const int lane = tid & 63;
  const int wave = tid >> 6;
  const int l15 = lane & 15, quad = lane >> 4;
  const int srow = lane >> 3;                   // 0..7
  const int scol = (((lane & 7) ^ srow) * 8);   // swizzled source col (elems)
  const int fxor = (l15 & 7) * 8;               // fragment-read XOR (elems)

  if (blk < 384) {
    // ---- projection GEMM: 128x64, K=1536 ----
    const int m0 = (blk & 63) * 128;
    const int n0 = (blk >> 6) * 64;
    const int wm = (wave & 1) * 64, wn = (wave >> 1) * 32;
    f32x4 acc[4][2] = {};
    for (int k0 = 0; k0 < 1536; k0 += 64) {
      const int ka = (k0 >= 1024) ? k0 - 1024 : k0;
#pragma unroll
      for (int i = 0; i < 4; ++i) {
        const int j = wave * 4 + i;
        const int r = j * 8 + srow;
        GLOAD_LDS16(qsplit + (size_t)(m0 + r) * 1024 + ka + scol, As + j * 512);
      }
#pragma unroll
      for (int i = 0; i < 2; ++i) {
        const int j = wave * 2 + i;
        const int r = j * 8 + srow;
        GLOAD_LDS16(Wcat + (size_t)(n0 + r) * 1536 + k0 + scol, Bs + j * 512);
      }
      __syncthreads();
#pragma unroll
      for (int ks = 0; ks < 2; ++ks) {
        bf16x8 af[4], bfr[2];
#pragma unroll
        for (int i = 0; i < 4; ++i)
          af[i] = *(const bf16x8*)&As[(wm + i * 16 + l15) * 64 + ((ks * 32 + quad * 8) ^ fxor)];
#pragma unroll
        for (int j = 0; j < 2; ++j)
          bfr[j] = *(const bf16x8*)&Bs[(wn + j * 16 + l15) * 64 + ((ks * 32 + quad * 8) ^ fxor)];
#pragma unroll
        for (int i = 0; i < 4; ++i)
#pragma unroll
          for (int j = 0; j < 2; ++j)
            acc[i][j] = __builtin_amdgcn_mfma_f32_16x16x32_bf16(af[i], bfr[j], acc[i][j], 0, 0, 0);
      }
      __syncthreads();
    }
#pragma unroll
    for (int i = 0; i < 4; ++i) {
      const int mbase = m0 + wm + i * 16 + quad * 4;
#pragma unroll
      for (int j = 0; j < 2; ++j) {
        const int n = n0 + wn + j * 16 + l15;
        const float bb = bias_cat[n];
#pragma unroll
        for (int r = 0; r < 4; ++r)
          projbuf[(size_t)(mbase + r) * 384 + n] = acc[i][j][r] + bb;
      }
    }
  } else {
    // ---- value projection GEMM: 128x128, K=512 ----
    const int vb = blk - 384;
    const int b = vb >> 7, rr = vb & 127;
    const int m0 = (rr >> 2) * 128;
    const int n0 = (rr & 3) * 128;
    const __hip_bfloat16* A = fmapT + (size_t)b * 4096 * 512;
    __hip_bfloat16* vout = vflat + (size_t)b * 8 * 4096 * 64;
    const int wm = (wave & 1) * 64, wn = (wave >> 1) * 64;
    f32x4 acc[4][4] = {};
    for (int k0 = 0; k0 < 512; k0 += 64) {
#pragma unroll
      for (int i = 0; i < 4; ++i) {
        const int j = wave * 4 + i;
        const int r = j * 8 + srow;
        GLOAD_LDS16(A + (size_t)(m0 + r) * 512 + k0 + scol, As + j * 512);
        GLOAD_LDS16(WvT + (size_t)(n0 + r) * 512 + k0 + scol, Bs + j * 512);
      }
      __syncthreads();
#pragma unroll
      for (int ks = 0; ks < 2; ++ks) {
        bf16x8 af[4], bfr[4];
#pragma unroll
        for (int i = 0; i < 4; ++i)
          af[i] = *(const bf16x8*)&As[(wm + i * 16 + l15) * 64 + ((ks * 32 + quad * 8) ^ fxor)];
#pragma unroll
        for (int j = 0; j < 4; ++j)
          bfr[j] = *(const bf16x8*)&Bs[(wn + j * 16 + l15) * 64 + ((ks * 32 + quad * 8) ^ fxor)];
#pragma unroll
        for (int i = 0; i < 4; ++i)
#pragma unroll
          for (int j = 0; j < 4; ++j)
            acc[i][j] = __builtin_amdgcn_mfma_f32_16x16x32_bf16(af[i], bfr[j], acc[i][j], 0, 0, 0);
      }
      __syncthreads();
    }
    // epilogue: retile C through LDS (swizzled, conflict-free) -> u16x8 stores
    unsigned short* Ct = lds;  // [128][128] bf16
#pragma unroll
    for (int i = 0; i < 4; ++i) {
#pragma unroll
      for (int j = 0; j < 4; ++j) {
        const int ngl = wn + j * 16 + l15;
#pragma unroll
        for (int r = 0; r < 4; ++r) {
          const int sl = wm + i * 16 + quad * 4 + r;
          BU u;
          u.b = __float2bfloat16(acc[i][j][r]);
          Ct[sl * 128 + (ngl ^ (((sl >> 2) & 3) * 16))] = u.u;
        }
      }
    }
    __syncthreads();
#pragma unroll
    for (int c = 0; c < 8; ++c) {
      const int sl = (tid >> 4) + c * 16;
      const int chunk = tid & 15;
      const int head = (n0 >> 6) + (chunk >> 3);
      const int dh = (chunk & 7) * 8;
      const int e = (chunk * 8) ^ (((sl >> 2) & 3) * 16);
      *(u16x8*)(vout + (size_t)head * (4096 * 64) + (size_t)(m0 + sl) * 64 + dh) =
          *(const u16x8*)&Ct[sl * 128 + e];
    }
  }
}

// ---------------------------------------------------------------------------
// Fused softmax + position math + bilinear gather.
// Block = (b,t) via XCD swizzle. Wave 0 computes the block's 8 heads x 16
// points of weights into LDS. Then 4 waves x 2 heads: lanes 0..31 points 0..7,
// lanes 32..63 points 8..15, lane covers dh pair (2k,2k+1) via uint loads of
// bf16 vflat; halves combined with shfl_xor(32).
// ---------------------------------------------------------------------------
__global__ __launch_bounds__(256) void sample_kernel(
    const float* __restrict__ ref_xy, const float* __restrict__ projbuf,
    const unsigned int* __restrict__ vflat2, unsigned int* __restrict__ ctx2) {
  __shared__ float4 wsm[8][16];  // {wx0, wx1, wy0*aw, wy1*aw}
  __shared__ int bsm[8][16];     // base dword index (yA*64+xA)*32
  const int blk = blockIdx.x;
  const int bt = (blk & 7) * 1024 + (blk >> 3);  // XCD-contiguous bt ranges
  const int b = bt >> 11;                        // T = 2048
  const int tid = threadIdx.x;
  const int wave = tid >> 6;
  const int lane = tid & 63;
  const int l31 = lane & 31;
  const bool hiHalf = lane >= 32;

  if (tid < 64) {
    const int h = tid >> 3, pi = tid & 7;
    const float ref_x = ref_xy[bt * 2 + 0];
    const float ref_y = ref_xy[bt * 2 + 1];
    const float* prow = projbuf + (size_t)bt * 384;
    const float* lg = prow + 256 + h * 16;
    float lv[16];
    float mx = -1e30f;
#pragma unroll
    for (int p = 0; p < 16; ++p) {
      lv[p] = lg[p];
      mx = fmaxf(mx, lv[p]);
    }
    float sum = 0.f;
#pragma unroll
    for (int p = 0; p < 16; ++p) {
      lv[p] = __expf(lv[p] - mx);
      sum += lv[p];
    }
    const float inv = 1.0f / sum;
    const float* of = prow + h * 32;
#pragma unroll
    for (int pq = 0; pq < 2; ++pq) {
      const int p = pi + pq * 8;
      const float aw = inv * lv[p];
      const float2 o2 = *(const float2*)&of[p * 2];
      const float ix = (ref_x + RADIUS * o2.x) * (float)(WFi - 1);
      const float iy = (ref_y + RADIUS * o2.y) * (float)(HFi - 1);
      const float ix0f = floorf(ix), iy0f = floorf(iy);
      const float fx = ix - ix0f, fy = iy - iy0f;
      const int ix0 = (int)ix0f, iy0 = (int)iy0f;

      float wx0 = 1.f - fx, wx1 = fx;
      float wy0 = 1.f - fy, wy1 = fy;
      if (ix0 == -1) { wx0 = fx; wx1 = 0.f; }
      if (ix0 == 63) { wx0 = 0.f; wx1 = 1.f - fx; }
      if (ix0 < -1 || ix0 > 63) { wx0 = 0.f; wx1 = 0.f; }
      if (iy0 == -1) { wy0 = fy; wy1 = 0.f; }
      if (iy0 == 63) { wy0 = 0.f; wy1 = 1.f - fy; }
      if (iy0 < -1 || iy0 > 63) { wy0 = 0.f; wy1 = 0.f; }
      const int xA = min(max(ix0, 0), WFi - 2);
      const int yA = min(max(iy0, 0), HFi - 2);

      wsm[h][p] = make_float4(wx0, wx1, wy0 * aw, wy1 * aw);
      bsm[h][p] = (yA * WFi + xA) * 32;
    }
  }
  __syncthreads();

  for (int h = wave; h < Hh; h += 4) {
    const float4* wq = &wsm[h][hiHalf ? 8 : 0];
    const int* bq = &bsm[h][hiHalf ? 8 : 0];
    const unsigned int* vb = vflat2 + (size_t)(b * 8 + h) * (4096 * 32) + l31;

    float acc0 = 0.f, acc1 = 0.f;
#pragma unroll
    for (int pp = 0; pp < 8; ++pp) {
      const float4 w4 = wq[pp];
      const unsigned int* r0 = vb + bq[pp];

      const unsigned int v00 = r0[0], v10 = r0[32];
      const unsigned int v01 = r0[2048], v11 = r0[2080];

      const float w00 = w4.x * w4.z, w10 = w4.y * w4.z;
      const float w01 = w4.x * w4.w, w11 = w4.y * w4.w;

      const float e00 = __uint_as_float(v00 << 16), o00 = __uint_as_float(v00 & 0xffff0000u);
      const float e10 = __uint_as_float(v10 << 16), o10 = __uint_as_float(v10 & 0xffff0000u);
      const float e01 = __uint_as_float(v01 << 16), o01 = __uint_as_float(v01 & 0xffff0000u);
      const float e11 = __uint_as_float(v11 << 16), o11 = __uint_as_float(v11 & 0xffff0000u);

      acc0 = fmaf(w00, e00, acc0);
      acc1 = fmaf(w00, o00, acc1);
      acc0 = fmaf(w10, e10, acc0);
      acc1 = fmaf(w10, o10, acc1);
      acc0 = fmaf(w01, e01, acc0);
      acc1 = fmaf(w01, o01, acc1);
      acc0 = fmaf(w11, e11, acc0);
      acc1 = fmaf(w11, o11, acc1);
    }

    acc0 += __shfl_xor(acc0, 32, 64);
    acc1 += __shfl_xor(acc1, 32, 64);
    if (!hiHalf) {
      BU c0, c1;
      c0.b = __float2bfloat16(acc0);
      c1.b = __float2bfloat16(acc1);
      ctx2[(size_t)bt * 256 + h * 32 + l31] = ((unsigned int)c1.u << 16) | c0.u;
    }
  }
}

// ---------------------------------------------------------------------------
// Output projection: C[m][n] = sum_k ctx[m*512+k] * WoutT[n*512+k] + b_out[n]
// 128x128 tile, BK=64, global_load_lds(16B) staging, full XOR-swizzled LDS.
// ---------------------------------------------------------------------------
__global__ __launch_bounds__(256) void outproj_kernel(
    const __hip_bfloat16* __restrict__ A, const __hip_bfloat16* __restrict__ Bm,
    const float* __restrict__ bias, float* __restrict__ C) {
  __shared__ unsigned short As[128 * 64];
  __shared__ unsigned short Bs[128 * 64];
  const int tid = threadIdx.x;
  const int lane = tid & 63;
  const int wave = tid >> 6;
  const int wm = (wave & 1) * 64, wn = (wave >> 1) * 64;
  const int l15 = lane & 15, quad = lane >> 4;
  const int m0 = blockIdx.x * 128, n0 = blockIdx.y * 128;
  const int srow = lane >> 3;
  const int scol = (((lane & 7) ^ srow) * 8);
  const int fxor = (l15 & 7) * 8;

  f32x4 acc[4][4] = {};

  for (int k0 = 0; k0 < 512; k0 += 64) {
#pragma unroll
    for (int i = 0; i < 4; ++i) {
      const int j = wave * 4 + i;
      const int r = j * 8 + srow;
      GLOAD_LDS16(A + (size_t)(m0 + r) * 512 + k0 + scol, As + j * 512);
      GLOAD_LDS16(Bm + (size_t)(n0 + r) * 512 + k0 + scol, Bs + j * 512);
    }
    __syncthreads();
#pragma unroll
    for (int ks = 0; ks < 2; ++ks) {
      bf16x8 af[4], bfr[4];
#pragma unroll
      for (int i = 0; i < 4; ++i)
        af[i] = *(const bf16x8*)&As[(wm + i * 16 + l15) * 64 + ((ks * 32 + quad * 8) ^ fxor)];
#pragma unroll
      for (int j = 0; j < 4; ++j)
        bfr[j] = *(const bf16x8*)&Bs[(wn + j * 16 + l15) * 64 + ((ks * 32 + quad * 8) ^ fxor)];
#pragma unroll
      for (int i = 0; i < 4; ++i)
#pragma unroll
        for (int j = 0; j < 4; ++j)
          acc[i][j] = __builtin_amdgcn_mfma_f32_16x16x32_bf16(af[i], bfr[j], acc[i][j], 0, 0, 0);
    }
    __syncthreads();
  }

#pragma unroll
  for (int i = 0; i < 4; ++i) {
    const int mbase = m0 + wm + i * 16 + quad * 4;
#pragma unroll
    for (int j = 0; j < 4; ++j) {
      const int n = n0 + wn + j * 16 + l15;
      const float bb = bias[n];
#pragma unroll
      for (int r = 0; r < 4; ++r)
        C[(size_t)(mbase + r) * 512 + n] = acc[i][j][r] + bb;
    }
  }
}

// ---------------------------------------------------------------------------
extern "C" void kernel_launch(void* const* d_in, const int* in_sizes, int n_in,
                              void* d_out, int out_size, void* d_ws, size_t ws_size,
                              hipStream_t stream) {
  const float* q      = (const float*)d_in[0];
  const float* fmap   = (const float*)d_in[1];
  const float* ref_xy = (const float*)d_in[2];
  const float* Wv     = (const float*)d_in[3];
  const float* W_off  = (const float*)d_in[4];
  const float* b_off  = (const float*)d_in[5];
  const float* W_w    = (const float*)d_in[6];
  const float* b_w    = (const float*)d_in[7];
  const float* W_out  = (const float*)d_in[8];
  const float* b_out  = (const float*)d_in[9];
  float* out = (float*)d_out;

  // workspace (no aliasing; ~71 MB total)
  char* ws = (char*)d_ws;
  __hip_bfloat16* qsplit = (__hip_bfloat16*)ws; ws += (size_t)8192 * 1024 * 2;
  __hip_bfloat16* Wcat   = (__hip_bfloat16*)ws; ws += (size_t)384 * 1536 * 2;
  float* bias_cat        = (float*)ws;          ws += 384 * 4;
  float* projbuf         = (float*)ws;          ws += (size_t)8192 * 384 * 4;
  __hip_bfloat16* fmapT  = (__hip_bfloat16*)ws; ws += (size_t)4 * 4096 * 512 * 2;
  __hip_bfloat16* WvT    = (__hip_bfloat16*)ws; ws += (size_t)512 * 512 * 2;
  __hip_bfloat16* WoutT  = (__hip_bfloat16*)ws; ws += (size_t)512 * 512 * 2;
  __hip_bfloat16* vflat  = (__hip_bfloat16*)ws; ws += (size_t)4 * 8 * 4096 * 64 * 2;
  __hip_bfloat16* ctxb   = (__hip_bfloat16*)ws; ws += (size_t)8192 * 512 * 2;

  // 1) fused prep: q split, Wcat/bias, weight + fmap transposes
  prep_kernel<<<dim3(8576), 256, 0, stream>>>(
      q, qsplit, W_off, W_w, b_off, b_w, Wcat, bias_cat, Wv, WvT, W_out, WoutT,
      fmap, fmapT);

  // 2) fused GEMMs: proj (384 long blocks FIRST) + value projection (512)
  fused_gemm<<<dim3(896), 256, 0, stream>>>(
      qsplit, Wcat, bias_cat, projbuf, fmapT, WvT, vflat);

  // 3) fused softmax + position math + bilinear gather -> ctx bf16
  sample_kernel<<<dim3(Bsz * T), 256, 0, stream>>>(
      ref_xy, projbuf, (const unsigned int*)vflat, (unsigned int*)ctxb);

  // 4) output projection + bias -> fp32 out
  outproj_kernel<<<dim3(64, 4), 256, 0, stream>>>(ctxb, WoutT, b_out, out);
}